// Round 2
// baseline (1872.303 us; speedup 1.0000x reference)
//
#include <hip/hip_runtime.h>
#include <stdint.h>

#define NCY 100000
#define NPR 50000
#define NT  150000
#define RREL 7
#define ETOT 2100000
#define EREL 300000
#define MAXDEG 24
#define NEG 0.2f

typedef __attribute__((ext_vector_type(8))) short short8;
typedef __attribute__((ext_vector_type(4))) float f32x4;
typedef unsigned short u16;

__device__ __forceinline__ float bf2f(u16 h){
  union{unsigned int u; float f;} v; v.u = ((unsigned int)h)<<16; return v.f;
}
__device__ __forceinline__ u16 f2bf(float f){
  union{unsigned int u; float f;} v; v.f=f;
  unsigned int u=v.u;
  return (u16)((u + 0x7fffu + ((u>>16)&1u))>>16);
}
__device__ __forceinline__ float lrelu(float x){ return x>0.f? x : NEG*x; }

#define MFMA(a,b,c) __builtin_amdgcn_mfma_f32_16x16x32_bf16(a,b,c,0,0,0)

// ---------------- bucket build for ONE relation: per-dst edge lists ----------------
__global__ __launch_bounds__(256) void k_build(const int* __restrict__ eidx, int rel,
                                               int* __restrict__ cnt, int* __restrict__ slots){
  int t = blockIdx.x*256 + threadIdx.x;
  if(t >= EREL) return;
  int e = rel*EREL + t;            // reference slices by position
  int dst = eidx[2*e+1];
  int pos = atomicAdd(&cnt[dst], 1);
  if(pos < MAXDEG) slots[dst*MAXDEG + pos] = e;
}

// ---------------- A_r = Wq_r Wk_r^T, u_r = Wq_r bk_r, w_r = Wk_r bq_r, c_r = bq.bk ----------------
__global__ __launch_bounds__(256) void k_prep(const float* __restrict__ Wq, const float* __restrict__ bq,
    const float* __restrict__ Wk, const float* __restrict__ bk,
    float* __restrict__ Ar, float* __restrict__ ur, float* __restrict__ wr,
    float* __restrict__ cr, int* __restrict__ bflag){
  int t = blockIdx.x*256 + threadIdx.x;
  if(t >= RREL*128*128) return;
  int r = t/(128*128); int ij = t - r*128*128; int i = ij>>7, j = ij&127;
  const float* wq = Wq + r*16384; const float* wk = Wk + r*16384;
  float s=0.f;
  for(int k=0;k<128;k++) s += wq[i*128+k]*wk[j*128+k];
  Ar[t] = s;
  if(i==0){
    float su=0.f, sw=0.f;
    for(int k=0;k<128;k++){ su += wq[j*128+k]*bk[r*128+k];
                            sw += wk[j*128+k]*bq[r*128+k]; }
    ur[r*128+j]=su; wr[r*128+j]=sw;
    if(j==0){
      float sc=0.f; int nz=0;
      for(int k=0;k<128;k++){ float a=bq[r*128+k], b2=bk[r*128+k];
        sc += a*b2; nz |= (a!=0.f)||(b2!=0.f); }
      cr[r]=sc; if(nz) atomicOr(bflag,1);
    }
  }
}

// ---------------- pack fp32 [K,128] matrices into bf16 MFMA B-fragment layout ----------------
struct PackJob{ const float* src; u16* dst; int ksteps; };
struct PackJobs{ PackJob j[20]; };
__global__ __launch_bounds__(256) void k_pack(PackJobs jobs){
  PackJob J = jobs.j[blockIdx.y];
  int t = blockIdx.x*256 + threadIdx.x;   // [0,4096): nt(8) x ks(8) x lane(64)
  int lane = t&63, ks=(t>>6)&7, nt=t>>9;
  if(ks >= J.ksteps) return;
  int col = nt*16 + (lane&15);
  int krow = ks*32 + (lane>>4)*8;
  u16* d = J.dst + ((nt*J.ksteps + ks)*64 + lane)*8;
  for(int j=0;j<8;j++) d[j] = f2bf(J.src[(krow+j)*128 + col]);
}

// ---------------- generic [M,128] @ [128,128] MFMA GEMM with fused epilogues ----------------
// EPI 0: emb -> bf16 emb16 (rowoff).           ASRC 1 (fp32 A)
// EPI 1: lrelu -> bf16 rs buffer.              ASRC 0 (bf16 A)
// EPI 2: score+accumulate: p=dot(P,rs)(+bias), e=exp((p+cr)*pri/sqrt(D));
//        acc += e*rs ; den += e.               ASRC 0 (A=emb16)
// EPI 3: final: out = C + bv + sig(skip)*gelu(emb16). A = acc/den (ASRC 2)
struct GArgs {
  const void* A; const u16* B; int M; int rowoff;
  u16* outH; float* acc; float* den;
  const u16* rs; const u16* emb16;
  const float* uvec; const float* wvec; const float* cr; const int* bflag; const float* pri;
  const float* bv; const float* skip;
};

template<int EPI, int ASRC>
__global__ __launch_bounds__(256) void k_gemm(GArgs G)
{
  int wave = threadIdx.x>>6, lane = threadIdx.x&63;
  int M = G.M;
  int base = blockIdx.x*64 + wave*16;
  if(base >= M) return;
  int arow = base + (lane&15); if(arow >= M) arow = M-1;
  int kof = (lane>>4)*8;
  short8 a[4];
  if(ASRC==0){
    const u16* A = (const u16*)G.A;
    #pragma unroll
    for(int ks=0;ks<4;ks++) a[ks] = *(const short8*)(A + (size_t)arow*128 + ks*32 + kof);
  } else {
    const float* A = (const float*)G.A;
    float sc = 1.f;
    if(ASRC==2) sc = 1.f/G.den[arow];
    #pragma unroll
    for(int ks=0;ks<4;ks++){
      const float* ap = A + (size_t)arow*128 + ks*32 + kof;
      f32x4 lo = *(const f32x4*)ap;
      f32x4 hi = *(const f32x4*)(ap+4);
      short8 s;
      #pragma unroll
      for(int j2=0;j2<4;j2++){ s[j2]=f2bf(lo[j2]*sc); s[4+j2]=f2bf(hi[j2]*sc); }
      a[ks]=s;
    }
  }
  f32x4 acc[8];
  #pragma unroll
  for(int nt=0;nt<8;nt++){
    f32x4 c = {0.f,0.f,0.f,0.f};
    #pragma unroll
    for(int ks=0;ks<4;ks++){
      short8 b = *(const short8*)(G.B + ((nt*4+ks)*64 + lane)*8);
      c = MFMA(a[ks], b, c);
    }
    acc[nt]=c;
  }
  int rbase = base + (lane>>4)*4;
  int cl = lane&15;
  if(EPI==0){
    #pragma unroll
    for(int nt=0;nt<8;nt++)
      for(int j=0;j<4;j++){
        int row=rbase+j;
        if(row<M){
          int col=nt*16+cl;
          G.outH[(size_t)(G.rowoff+row)*128+col] = f2bf(acc[nt][j]);
        }
      }
  } else if(EPI==1){
    #pragma unroll
    for(int nt=0;nt<8;nt++)
      for(int j=0;j<4;j++){
        int row=rbase+j;
        if(row<M){
          int col=nt*16+cl;
          G.outH[(size_t)row*128+col]=f2bf(lrelu(acc[nt][j]));
        }
      }
  } else if(EPI==2){
    float prival = G.pri[0] * 0.08838834764831845f; // pri / sqrt(128)
    int bias = *G.bflag;
    for(int j=0;j<4;j++){
      int row=rbase+j; bool ok = row<M;
      float p=0.f;
      if(ok){
        #pragma unroll
        for(int nt=0;nt<8;nt++){
          int col=nt*16+cl;
          p += acc[nt][j]*bf2f(G.rs[(size_t)row*128+col]);
        }
        if(bias){
          #pragma unroll
          for(int nt=0;nt<8;nt++){
            int col=nt*16+cl;
            p += bf2f(G.emb16[(size_t)row*128+col])*G.uvec[col]
               + bf2f(G.rs[(size_t)row*128+col])*G.wvec[col];
          }
        }
      }
      p += __shfl_xor(p,1,16); p += __shfl_xor(p,2,16);
      p += __shfl_xor(p,4,16); p += __shfl_xor(p,8,16);
      float e = __expf((p + G.cr[0])*prival);
      if(ok){
        #pragma unroll
        for(int nt=0;nt<8;nt++){
          int col=nt*16+cl; size_t o=(size_t)row*128+col;
          G.acc[o] += e*bf2f(G.rs[o]);
        }
        if(cl==0) G.den[row] += e;
      }
    }
  } else { // EPI==3
    float sg = 1.f/(1.f+__expf(-G.skip[0]));
    #pragma unroll
    for(int nt=0;nt<8;nt++)
      for(int j=0;j<4;j++){
        int row=rbase+j;
        if(row<M){
          int col=nt*16+cl;
          float x = bf2f(G.emb16[(size_t)row*128+col]);
          float g = 0.5f*x*(1.f+erff(x*0.70710678118f));
          G.acc[(size_t)row*128+col] = acc[nt][j] + G.bv[col] + sg*g;
        }
      }
  }
}

// ---------------- per-edge MFMA: temp = [emb[dst] | emb[src]] @ Wpair_r ; expv = exp(temp) ----------------
__global__ __launch_bounds__(256) void k_edge1(const u16* __restrict__ emb16,
    const u16* __restrict__ B, const int* __restrict__ eidx, int rel,
    u16* __restrict__ expv){
  int wave=threadIdx.x>>6, lane=threadIdx.x&63;
  int nt0=wave*2;
  short8 bW0[8], bW1[8];
  #pragma unroll
  for(int ks=0;ks<8;ks++){
    bW0[ks] = *(const short8*)(B + ((nt0*8+ks)*64+lane)*8);
    bW1[ks] = *(const short8*)(B + (((nt0+1)*8+ks)*64+lane)*8);
  }
  int kof=(lane>>4)*8;
  for(int tile=blockIdx.x; tile<EREL/16; tile+=gridDim.x){
    int e = rel*EREL + tile*16 + (lane&15);
    int src = eidx[2*e], dst = eidx[2*e+1];
    const u16* pd = emb16 + (size_t)dst*128 + kof;
    const u16* ps = emb16 + (size_t)src*128 + kof;
    f32x4 a0={0.f,0.f,0.f,0.f}, a1={0.f,0.f,0.f,0.f};
    #pragma unroll
    for(int ks=0;ks<4;ks++){
      short8 av = *(const short8*)(pd + ks*32);
      a0 = MFMA(av, bW0[ks], a0);
      a1 = MFMA(av, bW1[ks], a1);
    }
    #pragma unroll
    for(int ks=0;ks<4;ks++){
      short8 av = *(const short8*)(ps + ks*32);
      a0 = MFMA(av, bW0[4+ks], a0);
      a1 = MFMA(av, bW1[4+ks], a1);
    }
    int erow = tile*16 + (lane>>4)*4;
    #pragma unroll
    for(int j=0;j<4;j++){
      size_t o = (size_t)(erow+j)*128 + nt0*16 + (lane&15);
      expv[o]    = f2bf(__expf(a0[j]));
      expv[o+16] = f2bf(__expf(a1[j]));
    }
  }
}

// ---------------- per-dst gather: rs = lrelu( sum(x_j*ev) / sum(ev) ) ----------------
__global__ __launch_bounds__(256) void k_edge2(const u16* __restrict__ expv,
    const u16* __restrict__ emb16, const int* __restrict__ eidx,
    const int* __restrict__ cnt, const int* __restrict__ slots, int rel,
    u16* __restrict__ rsout){
  int n = blockIdx.x*2 + (threadIdx.x>>7);
  int d = threadIdx.x&127;
  int c = cnt[n]; c = c>MAXDEG? MAXDEG : c;
  const int* sl = slots + n*MAXDEG;
  float num=0.f, den=0.f;
  for(int i=0;i<c;i++){
    int e = sl[i];
    float ev = bf2f(expv[(size_t)(e - rel*EREL)*128 + d]);
    float xj = bf2f(emb16[(size_t)eidx[2*e]*128 + d]);
    num += xj*ev; den += ev;
  }
  rsout[(size_t)n*128+d] = f2bf(lrelu(num/(den+1e-16f)));
}

// ---------------- relation 3: t = sum(exp(w)*x_j)/sum(exp(w)) ----------------
__global__ __launch_bounds__(256) void k_rel3(const float* __restrict__ ew,
    const u16* __restrict__ emb16, const int* __restrict__ eidx,
    const int* __restrict__ cnt, const int* __restrict__ slots,
    u16* __restrict__ t16){
  int n = blockIdx.x*2 + (threadIdx.x>>7);
  int d = threadIdx.x&127;
  int c = cnt[n]; c = c>MAXDEG? MAXDEG : c;
  const int* sl = slots + n*MAXDEG;
  float num=0.f, den=0.f;
  for(int i=0;i<c;i++){
    int e = sl[i];
    float wv = __expf(ew[e]);
    num += wv * bf2f(emb16[(size_t)eidx[2*e]*128 + d]);
    den += wv;
  }
  t16[(size_t)n*128+d] = f2bf(num/(den+1e-16f));
}

extern "C" void kernel_launch(void* const* d_in, const int* in_sizes, int n_in,
                              void* d_out, int out_size, void* d_ws, size_t ws_size,
                              hipStream_t stream){
  const float* company = (const float*)d_in[0];
  const float* person  = (const float*)d_in[1];
  const float* eweight = (const float*)d_in[2];
  const float* W_com   = (const float*)d_in[3];
  const float* W_per   = (const float*)d_in[4];
  const float* Wq      = (const float*)d_in[5];
  const float* bq      = (const float*)d_in[6];
  const float* Wk      = (const float*)d_in[7];
  const float* bk      = (const float*)d_in[8];
  const float* Wv      = (const float*)d_in[9];
  const float* bvv     = (const float*)d_in[10];
  const float* pri     = (const float*)d_in[11];
  const float* Wpair   = (const float*)d_in[12];
  const float* Wrel3   = (const float*)d_in[13];
  const float* skip    = (const float*)d_in[14];
  const int*   eidx    = (const int*)d_in[15];
  float* out = (float*)d_out;

  // workspace layout (~171 MB total)
  char* w = (char*)d_ws;
  auto alloc = [&](size_t sz)->void*{ void* p=(void*)w; w += (sz+255)&~(size_t)255; return p; };
  u16*   emb16 = (u16*)alloc((size_t)NT*128*2);        // 38.4 MB
  u16*   expv  = (u16*)alloc((size_t)EREL*128*2);      // 76.8 MB (also holds t16 for rel 3)
  u16*   rs16  = (u16*)alloc((size_t)NT*128*2);        // 38.4 MB (per-relation, reused)
  float* den   = (float*)alloc((size_t)NT*4);          // 0.6 MB
  int*   cnt   = (int*)alloc((size_t)NT*4);            // 0.6 MB (per-relation, reused)
  int*   slots = (int*)alloc((size_t)NT*MAXDEG*4);     // 14.4 MB (per-relation, reused)
  float* Ar    = (float*)alloc((size_t)RREL*16384*4);  // 0.46 MB
  float* ur    = (float*)alloc(RREL*128*4);
  float* wr    = (float*)alloc(RREL*128*4);
  float* cr    = (float*)alloc(RREL*4);
  int*   bflag = (int*)alloc(256);
  u16* pWcom  = (u16*)alloc(16384*2);
  u16* pWper  = (u16*)alloc(16384*2);
  u16* pWrel3 = (u16*)alloc(16384*2);
  u16* pWv    = (u16*)alloc(16384*2);
  u16* pAr    = (u16*)alloc((size_t)RREL*16384*2);
  u16* pWpair = (u16*)alloc((size_t)RREL*32768*2);
  (void)ws_size; (void)in_sizes; (void)n_in; (void)out_size;

  hipMemsetAsync(d_out, 0, (size_t)NT*128*4, stream);   // acc lives in d_out
  hipMemsetAsync(den, 0, (size_t)NT*4, stream);
  hipMemsetAsync(bflag, 0, 4, stream);

  k_prep<<<(RREL*16384+255)/256,256,0,stream>>>(Wq,bq,Wk,bk,Ar,ur,wr,cr,bflag);

  PackJobs pj{};
  int nj=0;
  auto addjob=[&](const float* s,u16* d,int ks){ pj.j[nj].src=s; pj.j[nj].dst=d; pj.j[nj].ksteps=ks; nj++; };
  addjob(W_com,pWcom,4); addjob(W_per,pWper,4);
  addjob(Wrel3,pWrel3,4); addjob(Wv,pWv,4);
  for(int r=0;r<RREL;r++) addjob(Ar + (size_t)r*16384, pAr + (size_t)r*16384, 4);
  for(int r=0;r<RREL;r++) addjob(Wpair + (size_t)r*32768, pWpair + (size_t)r*32768, 8);
  dim3 pg(16, nj);
  k_pack<<<pg,256,0,stream>>>(pj);

  GArgs g{};
  // embedding GEMMs -> emb16 (bf16)
  g = GArgs{}; g.A=company; g.B=pWcom; g.M=NCY; g.rowoff=0; g.outH=emb16;
  k_gemm<0,1><<<(NCY+63)/64,256,0,stream>>>(g);
  g = GArgs{}; g.A=person; g.B=pWper; g.M=NPR; g.rowoff=NCY; g.outH=emb16;
  k_gemm<0,1><<<(NPR+63)/64,256,0,stream>>>(g);

  for(int r=0;r<RREL;r++){
    hipMemsetAsync(cnt, 0, (size_t)NT*4, stream);
    k_build<<<(EREL+255)/256,256,0,stream>>>(eidx, r, cnt, slots);
    if(r==3){
      k_rel3<<<NT/2,256,0,stream>>>(eweight,emb16,eidx,cnt,slots,expv /*as t16*/);
      g = GArgs{}; g.A=expv; g.B=pWrel3; g.M=NT; g.outH=rs16;
      k_gemm<1,0><<<(NT+63)/64,256,0,stream>>>(g);
    } else {
      k_edge1<<<1024,256,0,stream>>>(emb16, pWpair+(size_t)r*32768, eidx, r, expv);
      k_edge2<<<NT/2,256,0,stream>>>(expv,emb16,eidx,cnt,slots,r, rs16);
    }
    // score + online accumulate: acc(d_out) += exp(score_r)*rs_r ; den += exp(score_r)
    g = GArgs{}; g.A=emb16; g.B=pAr+(size_t)r*16384; g.M=NT;
    g.acc=out; g.den=den; g.rs=rs16; g.emb16=emb16;
    g.uvec=ur+(size_t)r*128; g.wvec=wr+(size_t)r*128; g.cr=cr+r; g.bflag=bflag; g.pri=pri+r;
    k_gemm<2,0><<<(NT+63)/64,256,0,stream>>>(g);
  }

  // final: out = (acc/den)@Wv + bv + sigmoid(skip)*gelu(emb)
  g = GArgs{}; g.A=out; g.B=pWv; g.M=NT;
  g.acc=out; g.den=den; g.emb16=emb16; g.bv=bvv; g.skip=skip;
  k_gemm<3,2><<<(NT+63)/64,256,0,stream>>>(g);
}

// Round 3
// 1493.868 us; speedup vs baseline: 1.2533x; 1.2533x over previous
//
#include <hip/hip_runtime.h>
#include <stdint.h>

#define NCY 100000
#define NPR 50000
#define NT  150000
#define RREL 7
#define ETOT 2100000
#define EREL 300000
#define NSEG (RREL*NT)          // 1,050,000 segment counters
#define NEG 0.2f

typedef __attribute__((ext_vector_type(8))) short short8;
typedef __attribute__((ext_vector_type(4))) float f32x4;
typedef __attribute__((ext_vector_type(4))) int   i32x4;
typedef unsigned short u16;

__device__ __forceinline__ float bf2f(u16 h){
  union{unsigned int u; float f;} v; v.u = ((unsigned int)h)<<16; return v.f;
}
__device__ __forceinline__ u16 f2bf(float f){
  union{unsigned int u; float f;} v; v.f=f;
  unsigned int u=v.u;
  return (u16)((u + 0x7fffu + ((u>>16)&1u))>>16);
}
__device__ __forceinline__ float lrelu(float x){ return x>0.f? x : NEG*x; }

#define MFMA(a,b,c) __builtin_amdgcn_mfma_f32_16x16x32_bf16(a,b,c,0,0,0)

// ================= counting sort: cnt -> scan -> scatter =================
__global__ __launch_bounds__(256) void k_cnt(const int* __restrict__ eidx,
                                             int* __restrict__ cnt){
  int e = blockIdx.x*256 + threadIdx.x;
  if(e >= ETOT) return;
  int r = e / EREL;
  int dst = eidx[2*e+1];
  atomicAdd(&cnt[r*NT + dst], 1);
}

#define SCAN_ENT 8192   // entries per block (256 thr x 32)
__global__ __launch_bounds__(256) void k_scanA(const int* __restrict__ cnt,
                                               int* __restrict__ bsum){
  __shared__ int lds[256];
  int t = threadIdx.x;
  int base = blockIdx.x*SCAN_ENT + t*32;
  int s = 0;
  #pragma unroll
  for(int k=0;k<32;k++){ int i = base+k; s += (i<NSEG)? cnt[i] : 0; }
  lds[t]=s; __syncthreads();
  for(int off=1; off<256; off<<=1){
    int a = (t>=off)? lds[t-off] : 0; __syncthreads();
    lds[t]+=a; __syncthreads();
  }
  if(t==255) bsum[blockIdx.x] = lds[255];
}

__global__ __launch_bounds__(256) void k_scanB(int* __restrict__ bsum, int nb,
                                               int* __restrict__ starts){
  __shared__ int lds[256];
  int t = threadIdx.x;
  int v = (t<nb)? bsum[t] : 0;
  lds[t]=v; __syncthreads();
  for(int off=1; off<256; off<<=1){
    int a = (t>=off)? lds[t-off] : 0; __syncthreads();
    lds[t]+=a; __syncthreads();
  }
  if(t<nb) bsum[t] = lds[t]-v;   // exclusive
  if(t==0) starts[NSEG] = ETOT;
}

__global__ __launch_bounds__(256) void k_scanC(const int* __restrict__ cnt,
                                               const int* __restrict__ bsum,
                                               int* __restrict__ starts,
                                               int* __restrict__ startm){
  __shared__ int lds[256];
  int t = threadIdx.x;
  int base = blockIdx.x*SCAN_ENT + t*32;
  int s = 0;
  #pragma unroll
  for(int k=0;k<32;k++){ int i = base+k; s += (i<NSEG)? cnt[i] : 0; }
  lds[t]=s; __syncthreads();
  for(int off=1; off<256; off<<=1){
    int a = (t>=off)? lds[t-off] : 0; __syncthreads();
    lds[t]+=a; __syncthreads();
  }
  int run = bsum[blockIdx.x] + lds[t]-s;   // exclusive prefix for this thread's chunk
  __syncthreads();
  for(int k=0;k<32;k++){
    int i = base+k;
    if(i<NSEG){ starts[i]=run; startm[i]=run; run += cnt[i]; }
  }
}

__global__ __launch_bounds__(256) void k_scatter(const int* __restrict__ eidx,
                                                 int* __restrict__ startm,
                                                 int* __restrict__ se){
  int e = blockIdx.x*256 + threadIdx.x;
  if(e >= ETOT) return;
  int r = e / EREL;
  int dst = eidx[2*e+1];
  int pos = atomicAdd(&startm[r*NT + dst], 1);
  se[pos] = e;
}

// ---------------- A_r = Wq_r Wk_r^T, u_r = Wq_r bk_r, w_r = Wk_r bq_r, c_r = bq.bk ----------------
__global__ __launch_bounds__(256) void k_prep(const float* __restrict__ Wq, const float* __restrict__ bq,
    const float* __restrict__ Wk, const float* __restrict__ bk,
    float* __restrict__ Ar, float* __restrict__ ur, float* __restrict__ wr,
    float* __restrict__ cr, int* __restrict__ bflag){
  int t = blockIdx.x*256 + threadIdx.x;
  if(t >= RREL*128*128) return;
  int r = t/(128*128); int ij = t - r*128*128; int i = ij>>7, j = ij&127;
  const float* wq = Wq + r*16384; const float* wk = Wk + r*16384;
  float s=0.f;
  for(int k=0;k<128;k++) s += wq[i*128+k]*wk[j*128+k];
  Ar[t] = s;
  if(i==0){
    float su=0.f, sw=0.f;
    for(int k=0;k<128;k++){ su += wq[j*128+k]*bk[r*128+k];
                            sw += wk[j*128+k]*bq[r*128+k]; }
    ur[r*128+j]=su; wr[r*128+j]=sw;
    if(j==0){
      float sc=0.f; int nz=0;
      for(int k=0;k<128;k++){ float a=bq[r*128+k], b2=bk[r*128+k];
        sc += a*b2; nz |= (a!=0.f)||(b2!=0.f); }
      cr[r]=sc; if(nz) atomicOr(bflag,1);
    }
  }
}

// ---------------- pack fp32 [K,128] matrices into bf16 MFMA B-fragment layout ----------------
struct PackJob{ const float* src; u16* dst; int ksteps; };
struct PackJobs{ PackJob j[20]; };
__global__ __launch_bounds__(256) void k_pack(PackJobs jobs){
  PackJob J = jobs.j[blockIdx.y];
  int t = blockIdx.x*256 + threadIdx.x;   // [0,4096): nt(8) x ks(8) x lane(64)
  int lane = t&63, ks=(t>>6)&7, nt=t>>9;
  if(ks >= J.ksteps) return;
  int col = nt*16 + (lane&15);
  int krow = ks*32 + (lane>>4)*8;
  u16* d = J.dst + ((nt*J.ksteps + ks)*64 + lane)*8;
  for(int j=0;j<8;j++) d[j] = f2bf(J.src[(krow+j)*128 + col]);
}

// ---------------- generic [M,128] @ [128,128] MFMA GEMM with fused epilogues ----------------
// EPI 0: emb -> bf16 emb16 (rowoff).           ASRC 1 (fp32 A)
// EPI 1: lrelu -> bf16 rs buffer.              ASRC 0 (bf16 A)
// EPI 2: score+accumulate: p=dot(P,rs)(+bias), e=exp((p+cr)*pri/sqrt(D));
//        acc += e*rs ; den += e.               ASRC 0 (A=emb16)
// EPI 3: final: out = C + bv + sig(skip)*gelu(emb16). A = acc/den (ASRC 2)
struct GArgs {
  const void* A; const u16* B; int M; int rowoff;
  u16* outH; float* acc; float* den;
  const u16* rs; const u16* emb16;
  const float* uvec; const float* wvec; const float* cr; const int* bflag; const float* pri;
  const float* bv; const float* skip;
};

template<int EPI, int ASRC>
__global__ __launch_bounds__(256) void k_gemm(GArgs G)
{
  int wave = threadIdx.x>>6, lane = threadIdx.x&63;
  int M = G.M;
  int base = blockIdx.x*64 + wave*16;
  if(base >= M) return;
  int arow = base + (lane&15); if(arow >= M) arow = M-1;
  int kof = (lane>>4)*8;
  short8 a[4];
  if(ASRC==0){
    const u16* A = (const u16*)G.A;
    #pragma unroll
    for(int ks=0;ks<4;ks++) a[ks] = *(const short8*)(A + (size_t)arow*128 + ks*32 + kof);
  } else {
    const float* A = (const float*)G.A;
    float sc = 1.f;
    if(ASRC==2) sc = 1.f/G.den[arow];
    #pragma unroll
    for(int ks=0;ks<4;ks++){
      const float* ap = A + (size_t)arow*128 + ks*32 + kof;
      f32x4 lo = *(const f32x4*)ap;
      f32x4 hi = *(const f32x4*)(ap+4);
      short8 s;
      #pragma unroll
      for(int j2=0;j2<4;j2++){ s[j2]=f2bf(lo[j2]*sc); s[4+j2]=f2bf(hi[j2]*sc); }
      a[ks]=s;
    }
  }
  f32x4 acc[8];
  #pragma unroll
  for(int nt=0;nt<8;nt++){
    f32x4 c = {0.f,0.f,0.f,0.f};
    #pragma unroll
    for(int ks=0;ks<4;ks++){
      short8 b = *(const short8*)(G.B + ((nt*4+ks)*64 + lane)*8);
      c = MFMA(a[ks], b, c);
    }
    acc[nt]=c;
  }
  int rbase = base + (lane>>4)*4;
  int cl = lane&15;
  if(EPI==0){
    #pragma unroll
    for(int nt=0;nt<8;nt++)
      for(int j=0;j<4;j++){
        int row=rbase+j;
        if(row<M){
          int col=nt*16+cl;
          G.outH[(size_t)(G.rowoff+row)*128+col] = f2bf(acc[nt][j]);
        }
      }
  } else if(EPI==1){
    #pragma unroll
    for(int nt=0;nt<8;nt++)
      for(int j=0;j<4;j++){
        int row=rbase+j;
        if(row<M){
          int col=nt*16+cl;
          G.outH[(size_t)row*128+col]=f2bf(lrelu(acc[nt][j]));
        }
      }
  } else if(EPI==2){
    float prival = G.pri[0] * 0.08838834764831845f; // pri / sqrt(128)
    int bias = *G.bflag;
    // cache rs rows in registers (single global read)
    float rsv[4][8];
    #pragma unroll
    for(int j=0;j<4;j++){
      int row=rbase+j; bool ok = row<M;
      #pragma unroll
      for(int nt=0;nt<8;nt++){
        int col=nt*16+cl;
        rsv[j][nt] = ok ? bf2f(G.rs[(size_t)row*128+col]) : 0.f;
      }
    }
    #pragma unroll
    for(int j=0;j<4;j++){
      int row=rbase+j; bool ok = row<M;
      float p=0.f;
      if(ok){
        #pragma unroll
        for(int nt=0;nt<8;nt++) p += acc[nt][j]*rsv[j][nt];
        if(bias){
          #pragma unroll
          for(int nt=0;nt<8;nt++){
            int col=nt*16+cl;
            p += bf2f(G.emb16[(size_t)row*128+col])*G.uvec[col]
               + rsv[j][nt]*G.wvec[col];
          }
        }
      }
      p += __shfl_xor(p,1,16); p += __shfl_xor(p,2,16);
      p += __shfl_xor(p,4,16); p += __shfl_xor(p,8,16);
      float e = __expf((p + G.cr[0])*prival);
      if(ok){
        #pragma unroll
        for(int nt=0;nt<8;nt++){
          int col=nt*16+cl; size_t o=(size_t)row*128+col;
          G.acc[o] += e*rsv[j][nt];
        }
        if(cl==0) G.den[row] += e;
      }
    }
  } else { // EPI==3
    float sg = 1.f/(1.f+__expf(-G.skip[0]));
    #pragma unroll
    for(int nt=0;nt<8;nt++)
      for(int j=0;j<4;j++){
        int row=rbase+j;
        if(row<M){
          int col=nt*16+cl;
          float x = bf2f(G.emb16[(size_t)row*128+col]);
          float g = 0.5f*x*(1.f+erff(x*0.70710678118f));
          G.acc[(size_t)row*128+col] = acc[nt][j] + G.bv[col] + sg*g;
        }
      }
  }
}

// ------- per-edge MFMA over dst-SORTED edges: expv[i] = exp([emb[dst]|emb[src]] @ Wpair) -------
__global__ __launch_bounds__(256) void k_edge1s(const u16* __restrict__ emb16,
    const u16* __restrict__ B, const int* __restrict__ eidx,
    const int* __restrict__ se_r, u16* __restrict__ expv){
  int wave=threadIdx.x>>6, lane=threadIdx.x&63;
  int nt0=wave*2;
  short8 bW0[8], bW1[8];
  #pragma unroll
  for(int ks=0;ks<8;ks++){
    bW0[ks] = *(const short8*)(B + ((nt0*8+ks)*64+lane)*8);
    bW1[ks] = *(const short8*)(B + (((nt0+1)*8+ks)*64+lane)*8);
  }
  int kof=(lane>>4)*8;
  for(int tile=blockIdx.x; tile<EREL/16; tile+=gridDim.x){
    int e = se_r[tile*16 + (lane&15)];
    int src = eidx[2*e], dst = eidx[2*e+1];
    const u16* pd = emb16 + (size_t)dst*128 + kof;
    const u16* ps = emb16 + (size_t)src*128 + kof;
    f32x4 a0={0.f,0.f,0.f,0.f}, a1={0.f,0.f,0.f,0.f};
    #pragma unroll
    for(int ks=0;ks<4;ks++){
      short8 av = *(const short8*)(pd + ks*32);
      a0 = MFMA(av, bW0[ks], a0);
      a1 = MFMA(av, bW1[ks], a1);
    }
    #pragma unroll
    for(int ks=0;ks<4;ks++){
      short8 av = *(const short8*)(ps + ks*32);
      a0 = MFMA(av, bW0[4+ks], a0);
      a1 = MFMA(av, bW1[4+ks], a1);
    }
    int erow = tile*16 + (lane>>4)*4;
    #pragma unroll
    for(int j=0;j<4;j++){
      size_t o = (size_t)(erow+j)*128 + nt0*16 + (lane&15);
      expv[o]    = f2bf(__expf(a0[j]));
      expv[o+16] = f2bf(__expf(a1[j]));
    }
  }
}

// ------- per-dst combine over sorted segment: rs = lrelu( sum(x_j*ev)/sum(ev) ) -------
// 16 threads per node, 8 cols each (short8). expv read is SEQUENTIAL.
__global__ __launch_bounds__(256) void k_edge2s(const u16* __restrict__ expv,
    const u16* __restrict__ emb16, const int* __restrict__ eidx,
    const int* __restrict__ se, const int* __restrict__ starts, int rel,
    u16* __restrict__ rsout){
  int n = blockIdx.x*16 + (threadIdx.x>>4);
  int dof = (threadIdx.x&15)*8;
  int s = starts[rel*NT + n];
  int e_end = starts[rel*NT + n + 1];
  float num[8]={0,0,0,0,0,0,0,0}, den[8]={0,0,0,0,0,0,0,0};
  for(int p=s; p<e_end; p++){
    int li = p - rel*EREL;
    int e = se[p];
    int src = eidx[2*e];
    short8 ev8 = *(const short8*)(expv + (size_t)li*128 + dof);
    short8 xj8 = *(const short8*)(emb16 + (size_t)src*128 + dof);
    #pragma unroll
    for(int j=0;j<8;j++){
      float ev = bf2f((u16)ev8[j]);
      num[j] += bf2f((u16)xj8[j])*ev;
      den[j] += ev;
    }
  }
  u16 o8[8];
  #pragma unroll
  for(int j=0;j<8;j++) o8[j] = f2bf(lrelu(num[j]/(den[j]+1e-16f)));
  *(short8*)(rsout + (size_t)n*128 + dof) = *(short8*)o8;
}

// ------- relation 3 over sorted segment: t = sum(exp(w)*x_j)/sum(exp(w)) -------
__global__ __launch_bounds__(256) void k_rel3s(const float* __restrict__ ew,
    const u16* __restrict__ emb16, const int* __restrict__ eidx,
    const int* __restrict__ se, const int* __restrict__ starts,
    u16* __restrict__ t16){
  int n = blockIdx.x*16 + (threadIdx.x>>4);
  int dof = (threadIdx.x&15)*8;
  int s = starts[3*NT + n];
  int e_end = starts[3*NT + n + 1];
  float num[8]={0,0,0,0,0,0,0,0}, den=0.f;
  for(int p=s; p<e_end; p++){
    int e = se[p];
    int src = eidx[2*e];
    float wv = __expf(ew[e]);
    den += wv;
    short8 xj8 = *(const short8*)(emb16 + (size_t)src*128 + dof);
    #pragma unroll
    for(int j=0;j<8;j++) num[j] += wv*bf2f((u16)xj8[j]);
  }
  float inv = 1.f/(den+1e-16f);
  u16 o8[8];
  #pragma unroll
  for(int j=0;j<8;j++) o8[j] = f2bf(num[j]*inv);
  *(short8*)(t16 + (size_t)n*128 + dof) = *(short8*)o8;
}

extern "C" void kernel_launch(void* const* d_in, const int* in_sizes, int n_in,
                              void* d_out, int out_size, void* d_ws, size_t ws_size,
                              hipStream_t stream){
  const float* company = (const float*)d_in[0];
  const float* person  = (const float*)d_in[1];
  const float* eweight = (const float*)d_in[2];
  const float* Wq      = (const float*)d_in[5];
  const float* bq      = (const float*)d_in[6];
  const float* Wk      = (const float*)d_in[7];
  const float* bk      = (const float*)d_in[8];
  const float* Wv      = (const float*)d_in[9];
  const float* bvv     = (const float*)d_in[10];
  const float* pri     = (const float*)d_in[11];
  const float* Wpair   = (const float*)d_in[12];
  const float* Wrel3   = (const float*)d_in[13];
  const float* skip    = (const float*)d_in[14];
  const int*   eidx    = (const int*)d_in[15];
  const float* W_com   = (const float*)d_in[3];
  const float* W_per   = (const float*)d_in[4];
  float* out = (float*)d_out;

  // workspace layout (~177 MB total)
  char* w = (char*)d_ws;
  auto alloc = [&](size_t sz)->void*{ void* p=(void*)w; w += (sz+255)&~(size_t)255; return p; };
  u16*   emb16 = (u16*)alloc((size_t)NT*128*2);        // 38.4 MB
  u16*   expv  = (u16*)alloc((size_t)EREL*128*2);      // 76.8 MB (reused as t16 for rel 3)
  u16*   rs16  = (u16*)alloc((size_t)NT*128*2);        // 38.4 MB (per-relation, reused)
  float* den   = (float*)alloc((size_t)NT*4);          // 0.6 MB
  int*   cnt   = (int*)alloc((size_t)NSEG*4);          // 4.2 MB
  int*   starts= (int*)alloc((size_t)(NSEG+1)*4);      // 4.2 MB
  int*   startm= (int*)alloc((size_t)NSEG*4);          // 4.2 MB
  int*   se    = (int*)alloc((size_t)ETOT*4);          // 8.4 MB
  int*   bsum  = (int*)alloc(1024);
  float* Ar    = (float*)alloc((size_t)RREL*16384*4);
  float* ur    = (float*)alloc(RREL*128*4);
  float* wr    = (float*)alloc(RREL*128*4);
  float* cr    = (float*)alloc(RREL*4);
  int*   bflag = (int*)alloc(256);
  u16* pWcom  = (u16*)alloc(16384*2);
  u16* pWper  = (u16*)alloc(16384*2);
  u16* pWrel3 = (u16*)alloc(16384*2);
  u16* pWv    = (u16*)alloc(16384*2);
  u16* pAr    = (u16*)alloc((size_t)RREL*16384*2);
  u16* pWpair = (u16*)alloc((size_t)RREL*32768*2);
  (void)ws_size; (void)in_sizes; (void)n_in; (void)out_size;

  hipMemsetAsync(d_out, 0, (size_t)NT*128*4, stream);   // acc lives in d_out
  hipMemsetAsync(den, 0, (size_t)NT*4, stream);
  hipMemsetAsync(cnt, 0, (size_t)NSEG*4, stream);
  hipMemsetAsync(bflag, 0, 4, stream);

  // counting sort of edges by (rel, dst)
  int nscan = (NSEG + SCAN_ENT - 1)/SCAN_ENT;   // 129
  k_cnt<<<(ETOT+255)/256,256,0,stream>>>(eidx, cnt);
  k_scanA<<<nscan,256,0,stream>>>(cnt, bsum);
  k_scanB<<<1,256,0,stream>>>(bsum, nscan, starts);
  k_scanC<<<nscan,256,0,stream>>>(cnt, bsum, starts, startm);
  k_scatter<<<(ETOT+255)/256,256,0,stream>>>(eidx, startm, se);

  k_prep<<<(RREL*16384+255)/256,256,0,stream>>>(Wq,bq,Wk,bk,Ar,ur,wr,cr,bflag);

  PackJobs pj{};
  int nj=0;
  auto addjob=[&](const float* s,u16* d,int ks){ pj.j[nj].src=s; pj.j[nj].dst=d; pj.j[nj].ksteps=ks; nj++; };
  addjob(W_com,pWcom,4); addjob(W_per,pWper,4);
  addjob(Wrel3,pWrel3,4); addjob(Wv,pWv,4);
  for(int r=0;r<RREL;r++) addjob(Ar + (size_t)r*16384, pAr + (size_t)r*16384, 4);
  for(int r=0;r<RREL;r++) addjob(Wpair + (size_t)r*32768, pWpair + (size_t)r*32768, 8);
  dim3 pg(16, nj);
  k_pack<<<pg,256,0,stream>>>(pj);

  GArgs g{};
  // embedding GEMMs -> emb16 (bf16)
  g = GArgs{}; g.A=company; g.B=pWcom; g.M=NCY; g.rowoff=0; g.outH=emb16;
  k_gemm<0,1><<<(NCY+63)/64,256,0,stream>>>(g);
  g = GArgs{}; g.A=person; g.B=pWper; g.M=NPR; g.rowoff=NCY; g.outH=emb16;
  k_gemm<0,1><<<(NPR+63)/64,256,0,stream>>>(g);

  for(int r=0;r<RREL;r++){
    if(r==3){
      k_rel3s<<<NT/16,256,0,stream>>>(eweight,emb16,eidx,se,starts,expv /*as t16*/);
      g = GArgs{}; g.A=expv; g.B=pWrel3; g.M=NT; g.outH=rs16;
      k_gemm<1,0><<<(NT+63)/64,256,0,stream>>>(g);
    } else {
      k_edge1s<<<1024,256,0,stream>>>(emb16, pWpair+(size_t)r*32768, eidx, se + (size_t)r*EREL, expv);
      k_edge2s<<<NT/16,256,0,stream>>>(expv,emb16,eidx,se,starts,r, rs16);
    }
    // score + online accumulate: acc(d_out) += exp(score_r)*rs_r ; den += exp(score_r)
    g = GArgs{}; g.A=emb16; g.B=pAr+(size_t)r*16384; g.M=NT;
    g.acc=out; g.den=den; g.rs=rs16; g.emb16=emb16;
    g.uvec=ur+(size_t)r*128; g.wvec=wr+(size_t)r*128; g.cr=cr+r; g.bflag=bflag; g.pri=pri+r;
    k_gemm<2,0><<<(NT+63)/64,256,0,stream>>>(g);
  }

  // final: out = (acc/den)@Wv + bv + sigmoid(skip)*gelu(emb)
  g = GArgs{}; g.A=out; g.B=pWv; g.M=NT;
  g.acc=out; g.den=den; g.emb16=emb16; g.bv=bvv; g.skip=skip;
  k_gemm<3,2><<<(NT+63)/64,256,0,stream>>>(g);
}

// Round 4
// 1230.935 us; speedup vs baseline: 1.5210x; 1.2136x over previous
//
#include <hip/hip_runtime.h>
#include <stdint.h>

#define NCY 100000
#define NPR 50000
#define NT  150000
#define RREL 7
#define ETOT 2100000
#define EREL 300000
#define NSEG (RREL*NT)          // 1,050,000 segment counters
#define NEG 0.2f

typedef __attribute__((ext_vector_type(8))) short short8;
typedef __attribute__((ext_vector_type(4))) float f32x4;
typedef unsigned short u16;

__device__ __forceinline__ float bf2f(u16 h){
  union{unsigned int u; float f;} v; v.u = ((unsigned int)h)<<16; return v.f;
}
__device__ __forceinline__ u16 f2bf(float f){
  union{unsigned int u; float f;} v; v.f=f;
  unsigned int u=v.u;
  return (u16)((u + 0x7fffu + ((u>>16)&1u))>>16);
}
__device__ __forceinline__ float lrelu(float x){ return x>0.f? x : NEG*x; }

#define MFMA(a,b,c) __builtin_amdgcn_mfma_f32_16x16x32_bf16(a,b,c,0,0,0)

// ================= counting sort: cnt -> scan -> scatter =================
__global__ __launch_bounds__(256) void k_cnt(const int* __restrict__ eidx,
                                             int* __restrict__ cnt){
  int e = blockIdx.x*256 + threadIdx.x;
  if(e >= ETOT) return;
  int r = e / EREL;
  int dst = eidx[2*e+1];
  atomicAdd(&cnt[r*NT + dst], 1);
}

#define SCAN_ENT 8192   // entries per block (256 thr x 32)
__global__ __launch_bounds__(256) void k_scanA(const int* __restrict__ cnt,
                                               int* __restrict__ bsum){
  __shared__ int lds[256];
  int t = threadIdx.x;
  int base = blockIdx.x*SCAN_ENT + t*32;
  int s = 0;
  #pragma unroll
  for(int k=0;k<32;k++){ int i = base+k; s += (i<NSEG)? cnt[i] : 0; }
  lds[t]=s; __syncthreads();
  for(int off=1; off<256; off<<=1){
    int a = (t>=off)? lds[t-off] : 0; __syncthreads();
    lds[t]+=a; __syncthreads();
  }
  if(t==255) bsum[blockIdx.x] = lds[255];
}

__global__ __launch_bounds__(256) void k_scanB(int* __restrict__ bsum, int nb,
                                               int* __restrict__ starts){
  __shared__ int lds[256];
  int t = threadIdx.x;
  int v = (t<nb)? bsum[t] : 0;
  lds[t]=v; __syncthreads();
  for(int off=1; off<256; off<<=1){
    int a = (t>=off)? lds[t-off] : 0; __syncthreads();
    lds[t]+=a; __syncthreads();
  }
  if(t<nb) bsum[t] = lds[t]-v;   // exclusive
  if(t==0) starts[NSEG] = ETOT;
}

__global__ __launch_bounds__(256) void k_scanC(const int* __restrict__ cnt,
                                               const int* __restrict__ bsum,
                                               int* __restrict__ starts,
                                               int* __restrict__ startm){
  __shared__ int lds[256];
  int t = threadIdx.x;
  int base = blockIdx.x*SCAN_ENT + t*32;
  int s = 0;
  #pragma unroll
  for(int k=0;k<32;k++){ int i = base+k; s += (i<NSEG)? cnt[i] : 0; }
  lds[t]=s; __syncthreads();
  for(int off=1; off<256; off<<=1){
    int a = (t>=off)? lds[t-off] : 0; __syncthreads();
    lds[t]+=a; __syncthreads();
  }
  int run = bsum[blockIdx.x] + lds[t]-s;   // exclusive prefix for this thread's chunk
  __syncthreads();
  for(int k=0;k<32;k++){
    int i = base+k;
    if(i<NSEG){ starts[i]=run; startm[i]=run; run += cnt[i]; }
  }
}

__global__ __launch_bounds__(256) void k_scatter(const int* __restrict__ eidx,
                                                 int* __restrict__ startm,
                                                 int* __restrict__ se){
  int e = blockIdx.x*256 + threadIdx.x;
  if(e >= ETOT) return;
  int r = e / EREL;
  int dst = eidx[2*e+1];
  int pos = atomicAdd(&startm[r*NT + dst], 1);
  se[pos] = e;
}

// ---------------- A_r = Wq_r Wk_r^T, u_r = Wq_r bk_r, w_r = Wk_r bq_r, c_r = bq.bk ----------------
__global__ __launch_bounds__(256) void k_prep(const float* __restrict__ Wq, const float* __restrict__ bq,
    const float* __restrict__ Wk, const float* __restrict__ bk,
    float* __restrict__ Ar, float* __restrict__ ur, float* __restrict__ wr,
    float* __restrict__ cr, int* __restrict__ bflag){
  int t = blockIdx.x*256 + threadIdx.x;
  if(t >= RREL*128*128) return;
  int r = t/(128*128); int ij = t - r*128*128; int i = ij>>7, j = ij&127;
  const float* wq = Wq + r*16384; const float* wk = Wk + r*16384;
  float s=0.f;
  for(int k=0;k<128;k++) s += wq[i*128+k]*wk[j*128+k];
  Ar[t] = s;
  if(i==0){
    float su=0.f, sw=0.f;
    for(int k=0;k<128;k++){ su += wq[j*128+k]*bk[r*128+k];
                            sw += wk[j*128+k]*bq[r*128+k]; }
    ur[r*128+j]=su; wr[r*128+j]=sw;
    if(j==0){
      float sc=0.f; int nz=0;
      for(int k=0;k<128;k++){ float a=bq[r*128+k], b2=bk[r*128+k];
        sc += a*b2; nz |= (a!=0.f)||(b2!=0.f); }
      cr[r]=sc; if(nz) atomicOr(bflag,1);
    }
  }
}

// ---------------- pack fp32 [K,128] matrices into bf16 MFMA B-fragment layout ----------------
struct PackJob{ const float* src; u16* dst; int ksteps; };
struct PackJobs{ PackJob j[20]; };
__global__ __launch_bounds__(256) void k_pack(PackJobs jobs){
  PackJob J = jobs.j[blockIdx.y];
  int t = blockIdx.x*256 + threadIdx.x;   // [0,4096): nt(8) x ks(8) x lane(64)
  int lane = t&63, ks=(t>>6)&7, nt=t>>9;
  if(ks >= J.ksteps) return;
  int col = nt*16 + (lane&15);
  int krow = ks*32 + (lane>>4)*8;
  u16* d = J.dst + ((nt*J.ksteps + ks)*64 + lane)*8;
  for(int j=0;j<8;j++) d[j] = f2bf(J.src[(krow+j)*128 + col]);
}

// ---------------- generic [M,128] @ [128,128] MFMA GEMM with fused epilogues ----------------
// EPI 0: emb -> bf16 emb16 (rowoff).           ASRC 1 (fp32 A)
// EPI 1: lrelu -> bf16 rs buffer.              ASRC 0 (bf16 A)
// EPI 2: score+accumulate: p=dot(P,rs)(+bias), e=exp((p+cr)*pri/sqrt(D));
//        acc += e*rs ; den += e.               ASRC 0 (A=emb16)
// EPI 3: final: out = C + bv + sig(skip)*gelu(emb16). A = acc/den (ASRC 2)
// EPI 4: exp -> bf16 (ebot for attention-weight cancellation trick)
struct GArgs {
  const void* A; const u16* B; int M; int rowoff;
  u16* outH; float* acc; float* den;
  const u16* rs; const u16* emb16;
  const float* uvec; const float* wvec; const float* cr; const int* bflag; const float* pri;
  const float* bv; const float* skip;
};

template<int EPI, int ASRC>
__global__ __launch_bounds__(256) void k_gemm(GArgs G)
{
  int wave = threadIdx.x>>6, lane = threadIdx.x&63;
  int M = G.M;
  int base = blockIdx.x*64 + wave*16;
  if(base >= M) return;
  int arow = base + (lane&15); if(arow >= M) arow = M-1;
  int kof = (lane>>4)*8;
  short8 a[4];
  if(ASRC==0){
    const u16* A = (const u16*)G.A;
    #pragma unroll
    for(int ks=0;ks<4;ks++) a[ks] = *(const short8*)(A + (size_t)arow*128 + ks*32 + kof);
  } else {
    const float* A = (const float*)G.A;
    float sc = 1.f;
    if(ASRC==2) sc = 1.f/G.den[arow];
    #pragma unroll
    for(int ks=0;ks<4;ks++){
      const float* ap = A + (size_t)arow*128 + ks*32 + kof;
      f32x4 lo = *(const f32x4*)ap;
      f32x4 hi = *(const f32x4*)(ap+4);
      short8 s;
      #pragma unroll
      for(int j2=0;j2<4;j2++){ s[j2]=f2bf(lo[j2]*sc); s[4+j2]=f2bf(hi[j2]*sc); }
      a[ks]=s;
    }
  }
  f32x4 acc[8];
  #pragma unroll
  for(int nt=0;nt<8;nt++){
    f32x4 c = {0.f,0.f,0.f,0.f};
    #pragma unroll
    for(int ks=0;ks<4;ks++){
      short8 b = *(const short8*)(G.B + ((nt*4+ks)*64 + lane)*8);
      c = MFMA(a[ks], b, c);
    }
    acc[nt]=c;
  }
  int rbase = base + (lane>>4)*4;
  int cl = lane&15;
  if(EPI==0){
    #pragma unroll
    for(int nt=0;nt<8;nt++)
      for(int j=0;j<4;j++){
        int row=rbase+j;
        if(row<M){
          int col=nt*16+cl;
          G.outH[(size_t)(G.rowoff+row)*128+col] = f2bf(acc[nt][j]);
        }
      }
  } else if(EPI==1){
    #pragma unroll
    for(int nt=0;nt<8;nt++)
      for(int j=0;j<4;j++){
        int row=rbase+j;
        if(row<M){
          int col=nt*16+cl;
          G.outH[(size_t)row*128+col]=f2bf(lrelu(acc[nt][j]));
        }
      }
  } else if(EPI==4){
    #pragma unroll
    for(int nt=0;nt<8;nt++)
      for(int j=0;j<4;j++){
        int row=rbase+j;
        if(row<M){
          int col=nt*16+cl;
          G.outH[(size_t)row*128+col]=f2bf(__expf(acc[nt][j]));
        }
      }
  } else if(EPI==2){
    float prival = G.pri[0] * 0.08838834764831845f; // pri / sqrt(128)
    int bias = *G.bflag;
    // cache rs rows in registers (single global read)
    float rsv[4][8];
    #pragma unroll
    for(int j=0;j<4;j++){
      int row=rbase+j; bool ok = row<M;
      #pragma unroll
      for(int nt=0;nt<8;nt++){
        int col=nt*16+cl;
        rsv[j][nt] = ok ? bf2f(G.rs[(size_t)row*128+col]) : 0.f;
      }
    }
    #pragma unroll
    for(int j=0;j<4;j++){
      int row=rbase+j; bool ok = row<M;
      float p=0.f;
      if(ok){
        #pragma unroll
        for(int nt=0;nt<8;nt++) p += acc[nt][j]*rsv[j][nt];
        if(bias){
          #pragma unroll
          for(int nt=0;nt<8;nt++){
            int col=nt*16+cl;
            p += bf2f(G.emb16[(size_t)row*128+col])*G.uvec[col]
               + rsv[j][nt]*G.wvec[col];
          }
        }
      }
      p += __shfl_xor(p,1,16); p += __shfl_xor(p,2,16);
      p += __shfl_xor(p,4,16); p += __shfl_xor(p,8,16);
      float e = __expf((p + G.cr[0])*prival);
      if(ok){
        #pragma unroll
        for(int nt=0;nt<8;nt++){
          int col=nt*16+cl; size_t o=(size_t)row*128+col;
          G.acc[o] += e*rsv[j][nt];
        }
        if(cl==0) G.den[row] += e;
      }
    }
  } else { // EPI==3
    float sg = 1.f/(1.f+__expf(-G.skip[0]));
    #pragma unroll
    for(int nt=0;nt<8;nt++)
      for(int j=0;j<4;j++){
        int row=rbase+j;
        if(row<M){
          int col=nt*16+cl;
          float x = bf2f(G.emb16[(size_t)row*128+col]);
          float g = 0.5f*x*(1.f+erff(x*0.70710678118f));
          G.acc[(size_t)row*128+col] = acc[nt][j] + G.bv[col] + sg*g;
        }
      }
  }
}

// ------- per-dst combine over sorted segment: rs = lrelu( sum(x_j*ev_j)/sum(ev_j) ) -------
// ev_j = ebot[src_j] (dst-half of the logit cancels in segment softmax).
// 16 threads per node, 8 cols each (short8). Gathers from L3-resident 38MB tables.
__global__ __launch_bounds__(256) void k_edge2s(const u16* __restrict__ ebot,
    const u16* __restrict__ emb16, const int* __restrict__ eidx,
    const int* __restrict__ se, const int* __restrict__ starts, int rel,
    u16* __restrict__ rsout){
  int n = blockIdx.x*16 + (threadIdx.x>>4);
  int dof = (threadIdx.x&15)*8;
  int s = starts[rel*NT + n];
  int e_end = starts[rel*NT + n + 1];
  float num[8]={0,0,0,0,0,0,0,0}, den[8]={0,0,0,0,0,0,0,0};
  for(int p=s; p<e_end; p++){
    int e = se[p];
    int src = eidx[2*e];
    short8 ev8 = *(const short8*)(ebot  + (size_t)src*128 + dof);
    short8 xj8 = *(const short8*)(emb16 + (size_t)src*128 + dof);
    #pragma unroll
    for(int j=0;j<8;j++){
      float ev = bf2f((u16)ev8[j]);
      num[j] += bf2f((u16)xj8[j])*ev;
      den[j] += ev;
    }
  }
  u16 o8[8];
  #pragma unroll
  for(int j=0;j<8;j++) o8[j] = f2bf(lrelu(num[j]/(den[j]+1e-16f)));
  *(short8*)(rsout + (size_t)n*128 + dof) = *(short8*)o8;
}

// ------- relation 3 over sorted segment: t = sum(exp(w)*x_j)/sum(exp(w)) -------
__global__ __launch_bounds__(256) void k_rel3s(const float* __restrict__ ew,
    const u16* __restrict__ emb16, const int* __restrict__ eidx,
    const int* __restrict__ se, const int* __restrict__ starts,
    u16* __restrict__ t16){
  int n = blockIdx.x*16 + (threadIdx.x>>4);
  int dof = (threadIdx.x&15)*8;
  int s = starts[3*NT + n];
  int e_end = starts[3*NT + n + 1];
  float num[8]={0,0,0,0,0,0,0,0}, den=0.f;
  for(int p=s; p<e_end; p++){
    int e = se[p];
    int src = eidx[2*e];
    float wv = __expf(ew[e]);
    den += wv;
    short8 xj8 = *(const short8*)(emb16 + (size_t)src*128 + dof);
    #pragma unroll
    for(int j=0;j<8;j++) num[j] += wv*bf2f((u16)xj8[j]);
  }
  float inv = 1.f/(den+1e-16f);
  u16 o8[8];
  #pragma unroll
  for(int j=0;j<8;j++) o8[j] = f2bf(num[j]*inv);
  *(short8*)(t16 + (size_t)n*128 + dof) = *(short8*)o8;
}

extern "C" void kernel_launch(void* const* d_in, const int* in_sizes, int n_in,
                              void* d_out, int out_size, void* d_ws, size_t ws_size,
                              hipStream_t stream){
  const float* company = (const float*)d_in[0];
  const float* person  = (const float*)d_in[1];
  const float* eweight = (const float*)d_in[2];
  const float* W_com   = (const float*)d_in[3];
  const float* W_per   = (const float*)d_in[4];
  const float* Wq      = (const float*)d_in[5];
  const float* bq      = (const float*)d_in[6];
  const float* Wk      = (const float*)d_in[7];
  const float* bk      = (const float*)d_in[8];
  const float* Wv      = (const float*)d_in[9];
  const float* bvv     = (const float*)d_in[10];
  const float* pri     = (const float*)d_in[11];
  const float* Wpair   = (const float*)d_in[12];
  const float* Wrel3   = (const float*)d_in[13];
  const float* skip    = (const float*)d_in[14];
  const int*   eidx    = (const int*)d_in[15];
  float* out = (float*)d_out;

  // workspace layout (~138 MB total)
  char* w = (char*)d_ws;
  auto alloc = [&](size_t sz)->void*{ void* p=(void*)w; w += (sz+255)&~(size_t)255; return p; };
  u16*   emb16 = (u16*)alloc((size_t)NT*128*2);        // 38.4 MB
  u16*   ebot  = (u16*)alloc((size_t)NT*128*2);        // 38.4 MB (exp(bot); reused as t16 for rel 3)
  u16*   rs16  = (u16*)alloc((size_t)NT*128*2);        // 38.4 MB (per-relation, reused)
  float* den   = (float*)alloc((size_t)NT*4);          // 0.6 MB
  int*   cnt   = (int*)alloc((size_t)NSEG*4);          // 4.2 MB
  int*   starts= (int*)alloc((size_t)(NSEG+1)*4);      // 4.2 MB
  int*   startm= (int*)alloc((size_t)NSEG*4);          // 4.2 MB
  int*   se    = (int*)alloc((size_t)ETOT*4);          // 8.4 MB
  int*   bsum  = (int*)alloc(1024);
  float* Ar    = (float*)alloc((size_t)RREL*16384*4);
  float* ur    = (float*)alloc(RREL*128*4);
  float* wr    = (float*)alloc(RREL*128*4);
  float* cr    = (float*)alloc(RREL*4);
  int*   bflag = (int*)alloc(256);
  u16* pWcom  = (u16*)alloc(16384*2);
  u16* pWper  = (u16*)alloc(16384*2);
  u16* pWrel3 = (u16*)alloc(16384*2);
  u16* pWv    = (u16*)alloc(16384*2);
  u16* pAr    = (u16*)alloc((size_t)RREL*16384*2);
  u16* pWbot  = (u16*)alloc((size_t)RREL*16384*2);     // bottom half of Wpair per relation
  (void)ws_size; (void)in_sizes; (void)n_in; (void)out_size;

  hipMemsetAsync(d_out, 0, (size_t)NT*128*4, stream);   // acc lives in d_out
  hipMemsetAsync(den, 0, (size_t)NT*4, stream);
  hipMemsetAsync(cnt, 0, (size_t)NSEG*4, stream);
  hipMemsetAsync(bflag, 0, 4, stream);

  // counting sort of edges by (rel, dst)
  int nscan = (NSEG + SCAN_ENT - 1)/SCAN_ENT;   // 129
  k_cnt<<<(ETOT+255)/256,256,0,stream>>>(eidx, cnt);
  k_scanA<<<nscan,256,0,stream>>>(cnt, bsum);
  k_scanB<<<1,256,0,stream>>>(bsum, nscan, starts);
  k_scanC<<<nscan,256,0,stream>>>(cnt, bsum, starts, startm);
  k_scatter<<<(ETOT+255)/256,256,0,stream>>>(eidx, startm, se);

  k_prep<<<(RREL*16384+255)/256,256,0,stream>>>(Wq,bq,Wk,bk,Ar,ur,wr,cr,bflag);

  PackJobs pj{};
  int nj=0;
  auto addjob=[&](const float* s,u16* d,int ks){ pj.j[nj].src=s; pj.j[nj].dst=d; pj.j[nj].ksteps=ks; nj++; };
  addjob(W_com,pWcom,4); addjob(W_per,pWper,4);
  addjob(Wrel3,pWrel3,4); addjob(Wv,pWv,4);
  for(int r=0;r<RREL;r++) addjob(Ar + (size_t)r*16384, pAr + (size_t)r*16384, 4);
  for(int r=0;r<RREL;r++) addjob(Wpair + (size_t)r*32768 + 16384, pWbot + (size_t)r*16384, 4);
  dim3 pg(16, nj);
  k_pack<<<pg,256,0,stream>>>(pj);

  GArgs g{};
  // embedding GEMMs -> emb16 (bf16)
  g = GArgs{}; g.A=company; g.B=pWcom; g.M=NCY; g.rowoff=0; g.outH=emb16;
  k_gemm<0,1><<<(NCY+63)/64,256,0,stream>>>(g);
  g = GArgs{}; g.A=person; g.B=pWper; g.M=NPR; g.rowoff=NCY; g.outH=emb16;
  k_gemm<0,1><<<(NPR+63)/64,256,0,stream>>>(g);

  for(int r=0;r<RREL;r++){
    if(r==3){
      k_rel3s<<<NT/16,256,0,stream>>>(eweight,emb16,eidx,se,starts,ebot /*as t16*/);
      g = GArgs{}; g.A=ebot; g.B=pWrel3; g.M=NT; g.outH=rs16;
      k_gemm<1,0><<<(NT+63)/64,256,0,stream>>>(g);
    } else {
      // ebot = exp(emb @ Wpair_bot[r]) : node-level GEMM, fused exp
      g = GArgs{}; g.A=emb16; g.B=pWbot+(size_t)r*16384; g.M=NT; g.outH=ebot;
      k_gemm<4,0><<<(NT+63)/64,256,0,stream>>>(g);
      k_edge2s<<<NT/16,256,0,stream>>>(ebot,emb16,eidx,se,starts,r, rs16);
    }
    // score + online accumulate: acc(d_out) += exp(score_r)*rs_r ; den += exp(score_r)
    g = GArgs{}; g.A=emb16; g.B=pAr+(size_t)r*16384; g.M=NT;
    g.acc=out; g.den=den; g.rs=rs16; g.emb16=emb16;
    g.uvec=ur+(size_t)r*128; g.wvec=wr+(size_t)r*128; g.cr=cr+r; g.bflag=bflag; g.pri=pri+r;
    k_gemm<2,0><<<(NT+63)/64,256,0,stream>>>(g);
  }

  // final: out = (acc/den)@Wv + bv + sigmoid(skip)*gelu(emb)
  g = GArgs{}; g.A=out; g.B=pWv; g.M=NT;
  g.acc=out; g.den=den; g.emb16=emb16; g.bv=bvv; g.skip=skip;
  k_gemm<3,2><<<(NT+63)/64,256,0,stream>>>(g);
}

// Round 5
// 1176.626 us; speedup vs baseline: 1.5912x; 1.0462x over previous
//
#include <hip/hip_runtime.h>
#include <stdint.h>

#define NCY 100000
#define NPR 50000
#define NT  150000
#define RREL 7
#define ETOT 2100000
#define EREL 300000
#define NSEG (RREL*NT)          // 1,050,000 segment counters
#define NEG 0.2f
#define NSH 8                   // XCD shards for scatter/count
#define NCHUNK 64

typedef __attribute__((ext_vector_type(8))) short short8;
typedef __attribute__((ext_vector_type(4))) float f32x4;
typedef unsigned short u16;

__device__ __forceinline__ float bf2f(u16 h){
  union{unsigned int u; float f;} v; v.u = ((unsigned int)h)<<16; return v.f;
}
__device__ __forceinline__ u16 f2bf(float f){
  union{unsigned int u; float f;} v; v.f=f;
  unsigned int u=v.u;
  return (u16)((u + 0x7fffu + ((u>>16)&1u))>>16);
}
__device__ __forceinline__ float lrelu(float x){ return x>0.f? x : NEG*x; }

#define MFMA(a,b,c) __builtin_amdgcn_mfma_f32_16x16x32_bf16(a,b,c,0,0,0)

// ============ counting sort, XCD-sharded: cnt -> scan -> scatter ============
// shard = blockIdx&7 maps to one XCD (round-robin heuristic): each shard
// handles a 1/8 dst-range so atomic/store windows are XCD-L2-local.
__global__ __launch_bounds__(256) void k_cnt(const int* __restrict__ eidx,
                                             int* __restrict__ cnt){
  int shard = blockIdx.x & 7;
  int chunk = blockIdx.x >> 3;
  int lo = shard*(NT/NSH), hi = (shard==NSH-1)? NT : lo + NT/NSH;
  const int CH = (ETOT + NCHUNK - 1)/NCHUNK;
  int e1 = min((chunk+1)*CH, ETOT);
  for(int e = chunk*CH + threadIdx.x; e < e1; e += 256){
    int2 sd = *(const int2*)(eidx + 2*e);
    if(sd.y < lo || sd.y >= hi) continue;
    int r = e / EREL;
    atomicAdd(&cnt[r*NT + sd.y], 1);
  }
}

#define SCAN_ENT 8192   // entries per block (256 thr x 32)
__global__ __launch_bounds__(256) void k_scanA(const int* __restrict__ cnt,
                                               int* __restrict__ bsum){
  __shared__ int lds[256];
  int t = threadIdx.x;
  int base = blockIdx.x*SCAN_ENT + t*32;
  int s = 0;
  #pragma unroll
  for(int k=0;k<32;k++){ int i = base+k; s += (i<NSEG)? cnt[i] : 0; }
  lds[t]=s; __syncthreads();
  for(int off=1; off<256; off<<=1){
    int a = (t>=off)? lds[t-off] : 0; __syncthreads();
    lds[t]+=a; __syncthreads();
  }
  if(t==255) bsum[blockIdx.x] = lds[255];
}

__global__ __launch_bounds__(256) void k_scanB(int* __restrict__ bsum, int nb,
                                               int* __restrict__ starts){
  __shared__ int lds[256];
  int t = threadIdx.x;
  int v = (t<nb)? bsum[t] : 0;
  lds[t]=v; __syncthreads();
  for(int off=1; off<256; off<<=1){
    int a = (t>=off)? lds[t-off] : 0; __syncthreads();
    lds[t]+=a; __syncthreads();
  }
  if(t<nb) bsum[t] = lds[t]-v;   // exclusive
  if(t==0) starts[NSEG] = ETOT;
}

__global__ __launch_bounds__(256) void k_scanC(const int* __restrict__ cnt,
                                               const int* __restrict__ bsum,
                                               int* __restrict__ starts,
                                               int* __restrict__ startm){
  __shared__ int lds[256];
  int t = threadIdx.x;
  int base = blockIdx.x*SCAN_ENT + t*32;
  int s = 0;
  #pragma unroll
  for(int k=0;k<32;k++){ int i = base+k; s += (i<NSEG)? cnt[i] : 0; }
  lds[t]=s; __syncthreads();
  for(int off=1; off<256; off<<=1){
    int a = (t>=off)? lds[t-off] : 0; __syncthreads();
    lds[t]+=a; __syncthreads();
  }
  int run = bsum[blockIdx.x] + lds[t]-s;   // exclusive prefix for this thread's chunk
  __syncthreads();
  for(int k=0;k<32;k++){
    int i = base+k;
    if(i<NSEG){ starts[i]=run; startm[i]=run; run += cnt[i]; }
  }
}

// scatter payloads: ssrc[pos] = src ; sew[pos-3*EREL] = edge_weight (rel 3 only)
__global__ __launch_bounds__(256) void k_scatter(const int* __restrict__ eidx,
                                                 const float* __restrict__ ew,
                                                 int* __restrict__ startm,
                                                 int* __restrict__ ssrc,
                                                 float* __restrict__ sew){
  int shard = blockIdx.x & 7;
  int chunk = blockIdx.x >> 3;
  int lo = shard*(NT/NSH), hi = (shard==NSH-1)? NT : lo + NT/NSH;
  const int CH = (ETOT + NCHUNK - 1)/NCHUNK;
  int e1 = min((chunk+1)*CH, ETOT);
  for(int e = chunk*CH + threadIdx.x; e < e1; e += 256){
    int2 sd = *(const int2*)(eidx + 2*e);
    if(sd.y < lo || sd.y >= hi) continue;
    int r = e / EREL;
    int pos = atomicAdd(&startm[r*NT + sd.y], 1);
    ssrc[pos] = sd.x;
    if(r==3) sew[pos - 3*EREL] = ew[e];
  }
}

// ---------------- A_r = Wq_r Wk_r^T, u_r = Wq_r bk_r, w_r = Wk_r bq_r, c_r = bq.bk ----------------
__global__ __launch_bounds__(256) void k_prep(const float* __restrict__ Wq, const float* __restrict__ bq,
    const float* __restrict__ Wk, const float* __restrict__ bk,
    float* __restrict__ Ar, float* __restrict__ ur, float* __restrict__ wr,
    float* __restrict__ cr, int* __restrict__ bflag){
  int t = blockIdx.x*256 + threadIdx.x;
  if(t >= RREL*128*128) return;
  int r = t/(128*128); int ij = t - r*128*128; int i = ij>>7, j = ij&127;
  const float* wq = Wq + r*16384; const float* wk = Wk + r*16384;
  float s=0.f;
  for(int k=0;k<128;k++) s += wq[i*128+k]*wk[j*128+k];
  Ar[t] = s;
  if(i==0){
    float su=0.f, sw=0.f;
    for(int k=0;k<128;k++){ su += wq[j*128+k]*bk[r*128+k];
                            sw += wk[j*128+k]*bq[r*128+k]; }
    ur[r*128+j]=su; wr[r*128+j]=sw;
    if(j==0){
      float sc=0.f; int nz=0;
      for(int k=0;k<128;k++){ float a=bq[r*128+k], b2=bk[r*128+k];
        sc += a*b2; nz |= (a!=0.f)||(b2!=0.f); }
      cr[r]=sc; if(nz) atomicOr(bflag,1);
    }
  }
}

// ---------------- pack fp32 [K,128] matrices into bf16 MFMA B-fragment layout ----------------
struct PackJob{ const float* src; u16* dst; int ksteps; };
struct PackJobs{ PackJob j[20]; };
__global__ __launch_bounds__(256) void k_pack(PackJobs jobs){
  PackJob J = jobs.j[blockIdx.y];
  int t = blockIdx.x*256 + threadIdx.x;   // [0,4096): nt(8) x ks(8) x lane(64)
  int lane = t&63, ks=(t>>6)&7, nt=t>>9;
  if(ks >= J.ksteps) return;
  int col = nt*16 + (lane&15);
  int krow = ks*32 + (lane>>4)*8;
  u16* d = J.dst + ((nt*J.ksteps + ks)*64 + lane)*8;
  for(int j=0;j<8;j++) d[j] = f2bf(J.src[(krow+j)*128 + col]);
}

// ---------------- generic [M,128] @ [128,128] MFMA GEMM with fused epilogues ----------------
// EPI 0: emb -> bf16 emb16 (rowoff).           ASRC 1 (fp32 A)
// EPI 1: lrelu -> bf16 rs buffer.              ASRC 0 (bf16 A)
// EPI 2: score+accumulate: p=dot(P,rs)(+bias), e=exp((p+cr)*pri/sqrt(D));
//        acc16(outH) += e*rs ; den += e.       ASRC 0 (A=emb16)
// EPI 3: final: out(acc) = C + bv + sig(skip)*gelu(emb16). A = acc16/den (ASRC 3)
// EPI 4: exp -> bf16 (ebot for attention-weight cancellation trick)
struct GArgs {
  const void* A; const u16* B; int M; int rowoff;
  u16* outH; float* acc; float* den;
  const u16* rs; const u16* emb16;
  const float* uvec; const float* wvec; const float* cr; const int* bflag; const float* pri;
  const float* bv; const float* skip;
};

template<int EPI, int ASRC>
__global__ __launch_bounds__(256) void k_gemm(GArgs G)
{
  int wave = threadIdx.x>>6, lane = threadIdx.x&63;
  int M = G.M;
  int base = blockIdx.x*64 + wave*16;
  if(base >= M) return;
  int arow = base + (lane&15); if(arow >= M) arow = M-1;
  int kof = (lane>>4)*8;
  short8 a[4];
  if(ASRC==0){
    const u16* A = (const u16*)G.A;
    #pragma unroll
    for(int ks=0;ks<4;ks++) a[ks] = *(const short8*)(A + (size_t)arow*128 + ks*32 + kof);
  } else if(ASRC==3){
    const u16* A = (const u16*)G.A;
    float sc = 1.f/G.den[arow];
    #pragma unroll
    for(int ks=0;ks<4;ks++){
      short8 v = *(const short8*)(A + (size_t)arow*128 + ks*32 + kof);
      short8 s;
      #pragma unroll
      for(int j2=0;j2<8;j2++) s[j2]=f2bf(bf2f((u16)v[j2])*sc);
      a[ks]=s;
    }
  } else {
    const float* A = (const float*)G.A;
    #pragma unroll
    for(int ks=0;ks<4;ks++){
      const float* ap = A + (size_t)arow*128 + ks*32 + kof;
      f32x4 lo = *(const f32x4*)ap;
      f32x4 hi = *(const f32x4*)(ap+4);
      short8 s;
      #pragma unroll
      for(int j2=0;j2<4;j2++){ s[j2]=f2bf(lo[j2]); s[4+j2]=f2bf(hi[j2]); }
      a[ks]=s;
    }
  }
  f32x4 acc[8];
  #pragma unroll
  for(int nt=0;nt<8;nt++){
    f32x4 c = {0.f,0.f,0.f,0.f};
    #pragma unroll
    for(int ks=0;ks<4;ks++){
      short8 b = *(const short8*)(G.B + ((nt*4+ks)*64 + lane)*8);
      c = MFMA(a[ks], b, c);
    }
    acc[nt]=c;
  }
  int rbase = base + (lane>>4)*4;
  int cl = lane&15;
  if(EPI==0){
    #pragma unroll
    for(int nt=0;nt<8;nt++)
      for(int j=0;j<4;j++){
        int row=rbase+j;
        if(row<M){
          int col=nt*16+cl;
          G.outH[(size_t)(G.rowoff+row)*128+col] = f2bf(acc[nt][j]);
        }
      }
  } else if(EPI==1){
    #pragma unroll
    for(int nt=0;nt<8;nt++)
      for(int j=0;j<4;j++){
        int row=rbase+j;
        if(row<M){
          int col=nt*16+cl;
          G.outH[(size_t)row*128+col]=f2bf(lrelu(acc[nt][j]));
        }
      }
  } else if(EPI==4){
    #pragma unroll
    for(int nt=0;nt<8;nt++)
      for(int j=0;j<4;j++){
        int row=rbase+j;
        if(row<M){
          int col=nt*16+cl;
          G.outH[(size_t)row*128+col]=f2bf(__expf(acc[nt][j]));
        }
      }
  } else if(EPI==2){
    float prival = G.pri[0] * 0.08838834764831845f; // pri / sqrt(128)
    int bias = *G.bflag;
    // cache rs rows in registers (single global read)
    float rsv[4][8];
    #pragma unroll
    for(int j=0;j<4;j++){
      int row=rbase+j; bool ok = row<M;
      #pragma unroll
      for(int nt=0;nt<8;nt++){
        int col=nt*16+cl;
        rsv[j][nt] = ok ? bf2f(G.rs[(size_t)row*128+col]) : 0.f;
      }
    }
    #pragma unroll
    for(int j=0;j<4;j++){
      int row=rbase+j; bool ok = row<M;
      float p=0.f;
      if(ok){
        #pragma unroll
        for(int nt=0;nt<8;nt++) p += acc[nt][j]*rsv[j][nt];
        if(bias){
          #pragma unroll
          for(int nt=0;nt<8;nt++){
            int col=nt*16+cl;
            p += bf2f(G.emb16[(size_t)row*128+col])*G.uvec[col]
               + rsv[j][nt]*G.wvec[col];
          }
        }
      }
      p += __shfl_xor(p,1,16); p += __shfl_xor(p,2,16);
      p += __shfl_xor(p,4,16); p += __shfl_xor(p,8,16);
      float e = __expf((p + G.cr[0])*prival);
      if(ok){
        #pragma unroll
        for(int nt=0;nt<8;nt++){
          int col=nt*16+cl; size_t o=(size_t)row*128+col;
          G.outH[o] = f2bf(bf2f(G.outH[o]) + e*rsv[j][nt]);   // bf16 acc RMW
        }
        if(cl==0) G.den[row] += e;
      }
    }
  } else { // EPI==3
    float sg = 1.f/(1.f+__expf(-G.skip[0]));
    #pragma unroll
    for(int nt=0;nt<8;nt++)
      for(int j=0;j<4;j++){
        int row=rbase+j;
        if(row<M){
          int col=nt*16+cl;
          float x = bf2f(G.emb16[(size_t)row*128+col]);
          float g = 0.5f*x*(1.f+erff(x*0.70710678118f));
          G.acc[(size_t)row*128+col] = acc[nt][j] + G.bv[col] + sg*g;
        }
      }
  }
}

// ------- per-dst combine over sorted segment: rs = lrelu( sum(x_j*ev_j)/sum(ev_j) ) -------
// ev_j = ebot[src_j] (dst-half of the logit cancels in segment softmax).
// 16 threads per node, 8 cols each (short8). ssrc read sequential; row gathers L3-hot.
__global__ __launch_bounds__(256) void k_edge2s(const u16* __restrict__ ebot,
    const u16* __restrict__ emb16, const int* __restrict__ ssrc,
    const int* __restrict__ starts, int rel,
    u16* __restrict__ rsout){
  int n = blockIdx.x*16 + (threadIdx.x>>4);
  int dof = (threadIdx.x&15)*8;
  int s = starts[rel*NT + n];
  int e_end = starts[rel*NT + n + 1];
  float num[8]={0,0,0,0,0,0,0,0}, den[8]={0,0,0,0,0,0,0,0};
  for(int p=s; p<e_end; p++){
    int src = ssrc[p];
    short8 ev8 = *(const short8*)(ebot  + (size_t)src*128 + dof);
    short8 xj8 = *(const short8*)(emb16 + (size_t)src*128 + dof);
    #pragma unroll
    for(int j=0;j<8;j++){
      float ev = bf2f((u16)ev8[j]);
      num[j] += bf2f((u16)xj8[j])*ev;
      den[j] += ev;
    }
  }
  u16 o8[8];
  #pragma unroll
  for(int j=0;j<8;j++) o8[j] = f2bf(lrelu(num[j]/(den[j]+1e-16f)));
  *(short8*)(rsout + (size_t)n*128 + dof) = *(short8*)o8;
}

// ------- relation 3 over sorted segment: t = sum(exp(w)*x_j)/sum(exp(w)) -------
__global__ __launch_bounds__(256) void k_rel3s(const float* __restrict__ sew,
    const u16* __restrict__ emb16, const int* __restrict__ ssrc,
    const int* __restrict__ starts,
    u16* __restrict__ t16){
  int n = blockIdx.x*16 + (threadIdx.x>>4);
  int dof = (threadIdx.x&15)*8;
  int s = starts[3*NT + n];
  int e_end = starts[3*NT + n + 1];
  float num[8]={0,0,0,0,0,0,0,0}, den=0.f;
  for(int p=s; p<e_end; p++){
    int src = ssrc[p];
    float wv = __expf(sew[p - 3*EREL]);
    den += wv;
    short8 xj8 = *(const short8*)(emb16 + (size_t)src*128 + dof);
    #pragma unroll
    for(int j=0;j<8;j++) num[j] += wv*bf2f((u16)xj8[j]);
  }
  float inv = 1.f/(den+1e-16f);
  u16 o8[8];
  #pragma unroll
  for(int j=0;j<8;j++) o8[j] = f2bf(num[j]*inv);
  *(short8*)(t16 + (size_t)n*128 + dof) = *(short8*)o8;
}

extern "C" void kernel_launch(void* const* d_in, const int* in_sizes, int n_in,
                              void* d_out, int out_size, void* d_ws, size_t ws_size,
                              hipStream_t stream){
  const float* company = (const float*)d_in[0];
  const float* person  = (const float*)d_in[1];
  const float* eweight = (const float*)d_in[2];
  const float* W_com   = (const float*)d_in[3];
  const float* W_per   = (const float*)d_in[4];
  const float* Wq      = (const float*)d_in[5];
  const float* bq      = (const float*)d_in[6];
  const float* Wk      = (const float*)d_in[7];
  const float* bk      = (const float*)d_in[8];
  const float* Wv      = (const float*)d_in[9];
  const float* bvv     = (const float*)d_in[10];
  const float* pri     = (const float*)d_in[11];
  const float* Wpair   = (const float*)d_in[12];
  const float* Wrel3   = (const float*)d_in[13];
  const float* skip    = (const float*)d_in[14];
  const int*   eidx    = (const int*)d_in[15];
  float* out = (float*)d_out;

  // workspace layout (~178 MB total)
  char* w = (char*)d_ws;
  auto alloc = [&](size_t sz)->void*{ void* p=(void*)w; w += (sz+255)&~(size_t)255; return p; };
  u16*   emb16 = (u16*)alloc((size_t)NT*128*2);        // 38.4 MB
  u16*   ebot  = (u16*)alloc((size_t)NT*128*2);        // 38.4 MB (exp(bot); reused as t16 for rel 3)
  u16*   rs16  = (u16*)alloc((size_t)NT*128*2);        // 38.4 MB (per-relation, reused)
  u16*   acc16 = (u16*)alloc((size_t)NT*128*2);        // 38.4 MB bf16 accumulator
  float* den   = (float*)alloc((size_t)NT*4);          // 0.6 MB
  int*   cnt   = (int*)alloc((size_t)NSEG*4);          // 4.2 MB
  int*   starts= (int*)alloc((size_t)(NSEG+1)*4);      // 4.2 MB
  int*   startm= (int*)alloc((size_t)NSEG*4);          // 4.2 MB
  int*   ssrc  = (int*)alloc((size_t)ETOT*4);          // 8.4 MB
  float* sew   = (float*)alloc((size_t)EREL*4);        // 1.2 MB
  int*   bsum  = (int*)alloc(1024);
  float* Ar    = (float*)alloc((size_t)RREL*16384*4);
  float* ur    = (float*)alloc(RREL*128*4);
  float* wr    = (float*)alloc(RREL*128*4);
  float* cr    = (float*)alloc(RREL*4);
  int*   bflag = (int*)alloc(256);
  u16* pWcom  = (u16*)alloc(16384*2);
  u16* pWper  = (u16*)alloc(16384*2);
  u16* pWrel3 = (u16*)alloc(16384*2);
  u16* pWv    = (u16*)alloc(16384*2);
  u16* pAr    = (u16*)alloc((size_t)RREL*16384*2);
  u16* pWbot  = (u16*)alloc((size_t)RREL*16384*2);     // bottom half of Wpair per relation
  (void)ws_size; (void)in_sizes; (void)n_in; (void)out_size;

  hipMemsetAsync(acc16, 0, (size_t)NT*128*2, stream);
  hipMemsetAsync(den, 0, (size_t)NT*4, stream);
  hipMemsetAsync(cnt, 0, (size_t)NSEG*4, stream);
  hipMemsetAsync(bflag, 0, 4, stream);

  // counting sort of edges by (rel, dst), XCD-sharded
  int nscan = (NSEG + SCAN_ENT - 1)/SCAN_ENT;   // 129
  k_cnt<<<NSH*NCHUNK,256,0,stream>>>(eidx, cnt);
  k_scanA<<<nscan,256,0,stream>>>(cnt, bsum);
  k_scanB<<<1,256,0,stream>>>(bsum, nscan, starts);
  k_scanC<<<nscan,256,0,stream>>>(cnt, bsum, starts, startm);
  k_scatter<<<NSH*NCHUNK,256,0,stream>>>(eidx, eweight, startm, ssrc, sew);

  k_prep<<<(RREL*16384+255)/256,256,0,stream>>>(Wq,bq,Wk,bk,Ar,ur,wr,cr,bflag);

  PackJobs pj{};
  int nj=0;
  auto addjob=[&](const float* s,u16* d,int ks){ pj.j[nj].src=s; pj.j[nj].dst=d; pj.j[nj].ksteps=ks; nj++; };
  addjob(W_com,pWcom,4); addjob(W_per,pWper,4);
  addjob(Wrel3,pWrel3,4); addjob(Wv,pWv,4);
  for(int r=0;r<RREL;r++) addjob(Ar + (size_t)r*16384, pAr + (size_t)r*16384, 4);
  for(int r=0;r<RREL;r++) addjob(Wpair + (size_t)r*32768 + 16384, pWbot + (size_t)r*16384, 4);
  dim3 pg(16, nj);
  k_pack<<<pg,256,0,stream>>>(pj);

  GArgs g{};
  // embedding GEMMs -> emb16 (bf16)
  g = GArgs{}; g.A=company; g.B=pWcom; g.M=NCY; g.rowoff=0; g.outH=emb16;
  k_gemm<0,1><<<(NCY+63)/64,256,0,stream>>>(g);
  g = GArgs{}; g.A=person; g.B=pWper; g.M=NPR; g.rowoff=NCY; g.outH=emb16;
  k_gemm<0,1><<<(NPR+63)/64,256,0,stream>>>(g);

  for(int r=0;r<RREL;r++){
    if(r==3){
      k_rel3s<<<NT/16,256,0,stream>>>(sew,emb16,ssrc,starts,ebot /*as t16*/);
      g = GArgs{}; g.A=ebot; g.B=pWrel3; g.M=NT; g.outH=rs16;
      k_gemm<1,0><<<(NT+63)/64,256,0,stream>>>(g);
    } else {
      // ebot = exp(emb @ Wpair_bot[r]) : node-level GEMM, fused exp
      g = GArgs{}; g.A=emb16; g.B=pWbot+(size_t)r*16384; g.M=NT; g.outH=ebot;
      k_gemm<4,0><<<(NT+63)/64,256,0,stream>>>(g);
      k_edge2s<<<NT/16,256,0,stream>>>(ebot,emb16,ssrc,starts,r, rs16);
    }
    // score + online accumulate: acc16 += exp(score_r)*rs_r ; den += exp(score_r)
    g = GArgs{}; g.A=emb16; g.B=pAr+(size_t)r*16384; g.M=NT;
    g.outH=acc16; g.den=den; g.rs=rs16; g.emb16=emb16;
    g.uvec=ur+(size_t)r*128; g.wvec=wr+(size_t)r*128; g.cr=cr+r; g.bflag=bflag; g.pri=pri+r;
    k_gemm<2,0><<<(NT+63)/64,256,0,stream>>>(g);
  }

  // final: out = (acc16/den)@Wv + bv + sigmoid(skip)*gelu(emb)
  g = GArgs{}; g.A=acc16; g.B=pWv; g.M=NT;
  g.acc=out; g.den=den; g.emb16=emb16; g.bv=bvv; g.skip=skip;
  k_gemm<3,3><<<(NT+63)/64,256,0,stream>>>(g);
}

// Round 7
// 1102.632 us; speedup vs baseline: 1.6980x; 1.0671x over previous
//
#include <hip/hip_runtime.h>
#include <stdint.h>

#define NCY 100000
#define NPR 50000
#define NT  150000
#define RREL 7
#define ETOT 2100000
#define EREL 300000
#define NSEG (RREL*NT)          // 1,050,000 segment counters
#define NEG 0.2f
#define NSH 8                   // XCD shards for scatter/count
#define NCHUNK 128

typedef __attribute__((ext_vector_type(8))) short short8;
typedef __attribute__((ext_vector_type(4))) float f32x4;
typedef __attribute__((ext_vector_type(2))) int   iv2;
typedef unsigned short u16;

__device__ __forceinline__ float bf2f(u16 h){
  union{unsigned int u; float f;} v; v.u = ((unsigned int)h)<<16; return v.f;
}
__device__ __forceinline__ u16 f2bf(float f){
  union{unsigned int u; float f;} v; v.f=f;
  unsigned int u=v.u;
  return (u16)((u + 0x7fffu + ((u>>16)&1u))>>16);
}
__device__ __forceinline__ float lrelu(float x){ return x>0.f? x : NEG*x; }

#define MFMA(a,b,c) __builtin_amdgcn_mfma_f32_16x16x32_bf16(a,b,c,0,0,0)

// ============ counting sort, XCD-sharded + nt streaming reads ============
// shard = blockIdx&7 -> one XCD (round-robin heuristic): each shard owns a
// 1/8 dst-range so its atomic/store window is XCD-L2-local. eidx is streamed
// with NON-TEMPORAL loads so it does not evict the write/atomic lines.
__global__ __launch_bounds__(256) void k_cnt(const int* __restrict__ eidx,
                                             int* __restrict__ cnt){
  int shard = blockIdx.x & 7;
  int chunk = blockIdx.x >> 3;
  int lo = shard*(NT/NSH), hi = (shard==NSH-1)? NT : lo + NT/NSH;
  const int CH = (ETOT + NCHUNK - 1)/NCHUNK;
  int e1 = min((chunk+1)*CH, ETOT);
  for(int e = chunk*CH + threadIdx.x; e < e1; e += 256){
    iv2 sd = __builtin_nontemporal_load((const iv2*)(eidx + 2*e));
    if(sd[1] < lo || sd[1] >= hi) continue;
    int r = e / EREL;
    atomicAdd(&cnt[r*NT + sd[1]], 1);
  }
}

#define SCAN_ENT 8192   // entries per block (256 thr x 32)
__global__ __launch_bounds__(256) void k_scanA(const int* __restrict__ cnt,
                                               int* __restrict__ bsum){
  __shared__ int lds[256];
  int t = threadIdx.x;
  int base = blockIdx.x*SCAN_ENT + t*32;
  int s = 0;
  #pragma unroll
  for(int k=0;k<32;k++){ int i = base+k; s += (i<NSEG)? cnt[i] : 0; }
  lds[t]=s; __syncthreads();
  for(int off=1; off<256; off<<=1){
    int a = (t>=off)? lds[t-off] : 0; __syncthreads();
    lds[t]+=a; __syncthreads();
  }
  if(t==255) bsum[blockIdx.x] = lds[255];
}

__global__ __launch_bounds__(256) void k_scanB(int* __restrict__ bsum, int nb,
                                               int* __restrict__ starts){
  __shared__ int lds[256];
  int t = threadIdx.x;
  int v = (t<nb)? bsum[t] : 0;
  lds[t]=v; __syncthreads();
  for(int off=1; off<256; off<<=1){
    int a = (t>=off)? lds[t-off] : 0; __syncthreads();
    lds[t]+=a; __syncthreads();
  }
  if(t<nb) bsum[t] = lds[t]-v;   // exclusive
  if(t==0) starts[NSEG] = ETOT;
}

__global__ __launch_bounds__(256) void k_scanC(const int* __restrict__ cnt,
                                               const int* __restrict__ bsum,
                                               int* __restrict__ starts,
                                               int* __restrict__ startm){
  __shared__ int lds[256];
  int t = threadIdx.x;
  int base = blockIdx.x*SCAN_ENT + t*32;
  int s = 0;
  #pragma unroll
  for(int k=0;k<32;k++){ int i = base+k; s += (i<NSEG)? cnt[i] : 0; }
  lds[t]=s; __syncthreads();
  for(int off=1; off<256; off<<=1){
    int a = (t>=off)? lds[t-off] : 0; __syncthreads();
    lds[t]+=a; __syncthreads();
  }
  int run = bsum[blockIdx.x] + lds[t]-s;   // exclusive prefix for this thread's chunk
  __syncthreads();
  for(int k=0;k<32;k++){
    int i = base+k;
    if(i<NSEG){ starts[i]=run; startm[i]=run; run += cnt[i]; }
  }
}

// scatter payloads: ssrc[pos] = src ; sew[pos-3*EREL] = edge_weight (rel 3 only)
__global__ __launch_bounds__(256) void k_scatter(const int* __restrict__ eidx,
                                                 const float* __restrict__ ew,
                                                 int* __restrict__ startm,
                                                 int* __restrict__ ssrc,
                                                 float* __restrict__ sew){
  int shard = blockIdx.x & 7;
  int chunk = blockIdx.x >> 3;
  int lo = shard*(NT/NSH), hi = (shard==NSH-1)? NT : lo + NT/NSH;
  const int CH = (ETOT + NCHUNK - 1)/NCHUNK;
  int e1 = min((chunk+1)*CH, ETOT);
  for(int e = chunk*CH + threadIdx.x; e < e1; e += 256){
    iv2 sd = __builtin_nontemporal_load((const iv2*)(eidx + 2*e));
    if(sd[1] < lo || sd[1] >= hi) continue;
    int r = e / EREL;
    int pos = atomicAdd(&startm[r*NT + sd[1]], 1);
    ssrc[pos] = sd[0];
    if(r==3) sew[pos - 3*EREL] = ew[e];
  }
}

// ---------------- A_r = Wq_r Wk_r^T, u_r = Wq_r bk_r, w_r = Wk_r bq_r, c_r = bq.bk ----------------
__global__ __launch_bounds__(256) void k_prep(const float* __restrict__ Wq, const float* __restrict__ bq,
    const float* __restrict__ Wk, const float* __restrict__ bk,
    float* __restrict__ Ar, float* __restrict__ ur, float* __restrict__ wr,
    float* __restrict__ cr, int* __restrict__ bflag){
  int t = blockIdx.x*256 + threadIdx.x;
  if(t >= RREL*128*128) return;
  int r = t/(128*128); int ij = t - r*128*128; int i = ij>>7, j = ij&127;
  const float* wq = Wq + r*16384; const float* wk = Wk + r*16384;
  float s=0.f;
  for(int k=0;k<128;k++) s += wq[i*128+k]*wk[j*128+k];
  Ar[t] = s;
  if(i==0){
    float su=0.f, sw=0.f;
    for(int k=0;k<128;k++){ su += wq[j*128+k]*bk[r*128+k];
                            sw += wk[j*128+k]*bq[r*128+k]; }
    ur[r*128+j]=su; wr[r*128+j]=sw;
    if(j==0){
      float sc=0.f; int nz=0;
      for(int k=0;k<128;k++){ float a=bq[r*128+k], b2=bk[r*128+k];
        sc += a*b2; nz |= (a!=0.f)||(b2!=0.f); }
      cr[r]=sc; if(nz) atomicOr(bflag,1);
    }
  }
}

// ---------------- pack fp32 [K,128] matrices into bf16 MFMA B-fragment layout ----------------
struct PackJob{ const float* src; u16* dst; int ksteps; };
struct PackJobs{ PackJob j[20]; };
__global__ __launch_bounds__(256) void k_pack(PackJobs jobs){
  PackJob J = jobs.j[blockIdx.y];
  int t = blockIdx.x*256 + threadIdx.x;   // [0,4096): nt(8) x ks(8) x lane(64)
  int lane = t&63, ks=(t>>6)&7, nt=t>>9;
  if(ks >= J.ksteps) return;
  int col = nt*16 + (lane&15);
  int krow = ks*32 + (lane>>4)*8;
  u16* d = J.dst + ((nt*J.ksteps + ks)*64 + lane)*8;
  for(int j=0;j<8;j++) d[j] = f2bf(J.src[(krow+j)*128 + col]);
}

// ---------------- generic [M,128] @ [128,128] MFMA GEMM with fused epilogues ----------------
// EPI 0: -> bf16 outH (rowoff).                ASRC 1 (fp32 A)
// EPI 1: lrelu -> bf16 outH.                   ASRC 0 (bf16 A)
// EPI 3: final: out(acc) = C + bv + sig(skip)*gelu(emb16). ASRC 3 (A=acc16/den)
struct GArgs {
  const void* A; const u16* B; int M; int rowoff;
  u16* outH; float* acc; float* den;
  const u16* emb16;
  const float* bv; const float* skip;
};

template<int EPI, int ASRC>
__global__ __launch_bounds__(256) void k_gemm(GArgs G)
{
  int wave = threadIdx.x>>6, lane = threadIdx.x&63;
  int M = G.M;
  int base = blockIdx.x*64 + wave*16;
  if(base >= M) return;
  int arow = base + (lane&15); if(arow >= M) arow = M-1;
  int kof = (lane>>4)*8;
  short8 a[4];
  if(ASRC==0){
    const u16* A = (const u16*)G.A;
    #pragma unroll
    for(int ks=0;ks<4;ks++) a[ks] = *(const short8*)(A + (size_t)arow*128 + ks*32 + kof);
  } else if(ASRC==3){
    const u16* A = (const u16*)G.A;
    float sc = 1.f/G.den[arow];
    #pragma unroll
    for(int ks=0;ks<4;ks++){
      short8 v = *(const short8*)(A + (size_t)arow*128 + ks*32 + kof);
      short8 s;
      #pragma unroll
      for(int j2=0;j2<8;j2++) s[j2]=f2bf(bf2f((u16)v[j2])*sc);
      a[ks]=s;
    }
  } else {
    const float* A = (const float*)G.A;
    #pragma unroll
    for(int ks=0;ks<4;ks++){
      const float* ap = A + (size_t)arow*128 + ks*32 + kof;
      f32x4 lo = *(const f32x4*)ap;
      f32x4 hi = *(const f32x4*)(ap+4);
      short8 s;
      #pragma unroll
      for(int j2=0;j2<4;j2++){ s[j2]=f2bf(lo[j2]); s[4+j2]=f2bf(hi[j2]); }
      a[ks]=s;
    }
  }
  f32x4 acc[8];
  #pragma unroll
  for(int nt=0;nt<8;nt++){
    f32x4 c = {0.f,0.f,0.f,0.f};
    #pragma unroll
    for(int ks=0;ks<4;ks++){
      short8 b = *(const short8*)(G.B + ((nt*4+ks)*64 + lane)*8);
      c = MFMA(a[ks], b, c);
    }
    acc[nt]=c;
  }
  int rbase = base + (lane>>4)*4;
  int cl = lane&15;
  if(EPI==0){
    #pragma unroll
    for(int nt=0;nt<8;nt++)
      for(int j=0;j<4;j++){
        int row=rbase+j;
        if(row<M){
          int col=nt*16+cl;
          G.outH[(size_t)(G.rowoff+row)*128+col] = f2bf(acc[nt][j]);
        }
      }
  } else if(EPI==1){
    #pragma unroll
    for(int nt=0;nt<8;nt++)
      for(int j=0;j<4;j++){
        int row=rbase+j;
        if(row<M){
          int col=nt*16+cl;
          G.outH[(size_t)row*128+col]=f2bf(lrelu(acc[nt][j]));
        }
      }
  } else { // EPI==3
    float sg = 1.f/(1.f+__expf(-G.skip[0]));
    #pragma unroll
    for(int nt=0;nt<8;nt++)
      for(int j=0;j<4;j++){
        int row=rbase+j;
        if(row<M){
          int col=nt*16+cl;
          float x = bf2f(G.emb16[(size_t)row*128+col]);
          float g = 0.5f*x*(1.f+erff(x*0.70710678118f));
          G.acc[(size_t)row*128+col] = acc[nt][j] + G.bv[col] + sg*g;
        }
      }
  }
}

// -------- fused per-relation: score+accumulate (EPI2) + optional ebot for NEXT relation --------
// score: P = emb@Ar ; p = dot(P, rs)(+bias) ; e = exp((p+cr)*pri/sqrt(D))
// acc16 += e*rs ; den += e.   HAS_EBOT: ebot_out = exp(emb@Wbot_next)  (shared A-frags)
struct FArgs {
  const u16* emb16; const u16* pA; const u16* pB2;
  const u16* rs; u16* acc16; float* den; u16* ebot;
  const float* uvec; const float* wvec; const float* cr; const int* bflag; const float* pri;
};

template<int HAS_EBOT>
__global__ __launch_bounds__(256) void k_facc(FArgs F)
{
  int wave = threadIdx.x>>6, lane = threadIdx.x&63;
  int base = blockIdx.x*64 + wave*16;
  if(base >= NT) return;
  int arow = base + (lane&15); if(arow >= NT) arow = NT-1;
  int kof = (lane>>4)*8;
  short8 a[4];
  #pragma unroll
  for(int ks=0;ks<4;ks++) a[ks] = *(const short8*)(F.emb16 + (size_t)arow*128 + ks*32 + kof);
  int rbase = base + (lane>>4)*4;
  int cl = lane&15;
  // optional: ebot for next relation (shares A-fragments), write and free regs
  if(HAS_EBOT){
    #pragma unroll
    for(int nt=0;nt<8;nt++){
      f32x4 c = {0.f,0.f,0.f,0.f};
      #pragma unroll
      for(int ks=0;ks<4;ks++){
        short8 b = *(const short8*)(F.pB2 + ((nt*4+ks)*64 + lane)*8);
        c = MFMA(a[ks], b, c);
      }
      #pragma unroll
      for(int j=0;j<4;j++){
        int row=rbase+j;
        if(row<NT) F.ebot[(size_t)row*128 + nt*16+cl] = f2bf(__expf(c[j]));
      }
    }
  }
  // score GEMM
  f32x4 accS[8];
  #pragma unroll
  for(int nt=0;nt<8;nt++){
    f32x4 c = {0.f,0.f,0.f,0.f};
    #pragma unroll
    for(int ks=0;ks<4;ks++){
      short8 b = *(const short8*)(F.pA + ((nt*4+ks)*64 + lane)*8);
      c = MFMA(a[ks], b, c);
    }
    accS[nt]=c;
  }
  float prival = F.pri[0] * 0.08838834764831845f; // pri / sqrt(128)
  int bias = *F.bflag;
  float rsv[4][8];
  #pragma unroll
  for(int j=0;j<4;j++){
    int row=rbase+j; bool ok = row<NT;
    #pragma unroll
    for(int nt=0;nt<8;nt++){
      int col=nt*16+cl;
      rsv[j][nt] = ok ? bf2f(F.rs[(size_t)row*128+col]) : 0.f;
    }
  }
  #pragma unroll
  for(int j=0;j<4;j++){
    int row=rbase+j; bool ok = row<NT;
    float p=0.f;
    if(ok){
      #pragma unroll
      for(int nt=0;nt<8;nt++) p += accS[nt][j]*rsv[j][nt];
      if(bias){
        #pragma unroll
        for(int nt=0;nt<8;nt++){
          int col=nt*16+cl;
          p += bf2f(F.emb16[(size_t)row*128+col])*F.uvec[col]
             + rsv[j][nt]*F.wvec[col];
        }
      }
    }
    p += __shfl_xor(p,1,16); p += __shfl_xor(p,2,16);
    p += __shfl_xor(p,4,16); p += __shfl_xor(p,8,16);
    float e = __expf((p + F.cr[0])*prival);
    if(ok){
      #pragma unroll
      for(int nt=0;nt<8;nt++){
        size_t o=(size_t)row*128 + nt*16+cl;
        F.acc16[o] = f2bf(bf2f(F.acc16[o]) + e*rsv[j][nt]);   // bf16 acc RMW
      }
      if(cl==0) F.den[row] += e;
    }
  }
}

// ------- per-dst combine over sorted segment: rs = lrelu( sum(x_j*ev_j)/sum(ev_j) ) -------
// ev_j = ebot[src_j] (dst-half of the logit cancels in segment softmax).
// 16 threads per node, 8 cols each. Pair-unrolled for gather ILP.
__global__ __launch_bounds__(256) void k_edge2s(const u16* __restrict__ ebot,
    const u16* __restrict__ emb16, const int* __restrict__ ssrc,
    const int* __restrict__ starts, int rel,
    u16* __restrict__ rsout){
  int n = blockIdx.x*16 + (threadIdx.x>>4);
  int dof = (threadIdx.x&15)*8;
  int s = starts[rel*NT + n];
  int e_end = starts[rel*NT + n + 1];
  float num[8]={0,0,0,0,0,0,0,0}, den[8]={0,0,0,0,0,0,0,0};
  int p = s;
  for(; p+1 < e_end; p += 2){
    int s0 = ssrc[p], s1 = ssrc[p+1];
    short8 ev0 = *(const short8*)(ebot  + (size_t)s0*128 + dof);
    short8 xj0 = *(const short8*)(emb16 + (size_t)s0*128 + dof);
    short8 ev1 = *(const short8*)(ebot  + (size_t)s1*128 + dof);
    short8 xj1 = *(const short8*)(emb16 + (size_t)s1*128 + dof);
    #pragma unroll
    for(int j=0;j<8;j++){
      float e0 = bf2f((u16)ev0[j]), e1 = bf2f((u16)ev1[j]);
      num[j] += bf2f((u16)xj0[j])*e0 + bf2f((u16)xj1[j])*e1;
      den[j] += e0 + e1;
    }
  }
  if(p < e_end){
    int s0 = ssrc[p];
    short8 ev0 = *(const short8*)(ebot  + (size_t)s0*128 + dof);
    short8 xj0 = *(const short8*)(emb16 + (size_t)s0*128 + dof);
    #pragma unroll
    for(int j=0;j<8;j++){
      float e0 = bf2f((u16)ev0[j]);
      num[j] += bf2f((u16)xj0[j])*e0;
      den[j] += e0;
    }
  }
  u16 o8[8];
  #pragma unroll
  for(int j=0;j<8;j++) o8[j] = f2bf(lrelu(num[j]/(den[j]+1e-16f)));
  *(short8*)(rsout + (size_t)n*128 + dof) = *(short8*)o8;
}

// ------- relation 3 over sorted segment: t = sum(exp(w)*x_j)/sum(exp(w)) -------
__global__ __launch_bounds__(256) void k_rel3s(const float* __restrict__ sew,
    const u16* __restrict__ emb16, const int* __restrict__ ssrc,
    const int* __restrict__ starts,
    u16* __restrict__ t16){
  int n = blockIdx.x*16 + (threadIdx.x>>4);
  int dof = (threadIdx.x&15)*8;
  int s = starts[3*NT + n];
  int e_end = starts[3*NT + n + 1];
  float num[8]={0,0,0,0,0,0,0,0}, den=0.f;
  for(int p=s; p<e_end; p++){
    int src = ssrc[p];
    float wv = __expf(sew[p - 3*EREL]);
    den += wv;
    short8 xj8 = *(const short8*)(emb16 + (size_t)src*128 + dof);
    #pragma unroll
    for(int j=0;j<8;j++) num[j] += wv*bf2f((u16)xj8[j]);
  }
  float inv = 1.f/(den+1e-16f);
  u16 o8[8];
  #pragma unroll
  for(int j=0;j<8;j++) o8[j] = f2bf(num[j]*inv);
  *(short8*)(t16 + (size_t)n*128 + dof) = *(short8*)o8;
}

extern "C" void kernel_launch(void* const* d_in, const int* in_sizes, int n_in,
                              void* d_out, int out_size, void* d_ws, size_t ws_size,
                              hipStream_t stream){
  const float* company = (const float*)d_in[0];
  const float* person  = (const float*)d_in[1];
  const float* eweight = (const float*)d_in[2];
  const float* W_com   = (const float*)d_in[3];
  const float* W_per   = (const float*)d_in[4];
  const float* Wq      = (const float*)d_in[5];
  const float* bq      = (const float*)d_in[6];
  const float* Wk      = (const float*)d_in[7];
  const float* bk      = (const float*)d_in[8];
  const float* Wv      = (const float*)d_in[9];
  const float* bvv     = (const float*)d_in[10];
  const float* pri     = (const float*)d_in[11];
  const float* Wpair   = (const float*)d_in[12];
  const float* Wrel3   = (const float*)d_in[13];
  const float* skip    = (const float*)d_in[14];
  const int*   eidx    = (const int*)d_in[15];
  float* out = (float*)d_out;

  // workspace layout (~178 MB total; ws_size known-good at this level)
  char* w = (char*)d_ws;
  auto alloc = [&](size_t sz)->void*{ void* p=(void*)w; w += (sz+255)&~(size_t)255; return p; };
  u16*   emb16 = (u16*)alloc((size_t)NT*128*2);        // 38.4 MB
  u16*   ebot  = (u16*)alloc((size_t)NT*128*2);        // 38.4 MB (exp(bot) / t16)
  u16*   rs16  = (u16*)alloc((size_t)NT*128*2);        // 38.4 MB (per-relation, reused)
  u16*   acc16 = (u16*)alloc((size_t)NT*128*2);        // 38.4 MB bf16 accumulator
  float* den   = (float*)alloc((size_t)NT*4);          // 0.6 MB
  int*   cnt   = (int*)alloc((size_t)NSEG*4);          // 4.2 MB
  int*   starts= (int*)alloc((size_t)(NSEG+1)*4);      // 4.2 MB
  int*   startm= (int*)alloc((size_t)NSEG*4);          // 4.2 MB
  int*   ssrc  = (int*)alloc((size_t)ETOT*4);          // 8.4 MB
  float* sew   = (float*)alloc((size_t)EREL*4);        // 1.2 MB
  int*   bsum  = (int*)alloc(1024);
  float* Ar    = (float*)alloc((size_t)RREL*16384*4);
  float* ur    = (float*)alloc(RREL*128*4);
  float* wr    = (float*)alloc(RREL*128*4);
  float* cr    = (float*)alloc(RREL*4);
  int*   bflag = (int*)alloc(256);
  u16* pWcom  = (u16*)alloc(16384*2);
  u16* pWper  = (u16*)alloc(16384*2);
  u16* pWrel3 = (u16*)alloc(16384*2);
  u16* pWv    = (u16*)alloc(16384*2);
  u16* pAr    = (u16*)alloc((size_t)RREL*16384*2);
  u16* pWbot  = (u16*)alloc((size_t)6*16384*2);        // bottom Wpair half, att rels only
  (void)ws_size; (void)in_sizes; (void)n_in; (void)out_size;

  hipMemsetAsync(acc16, 0, (size_t)NT*128*2, stream);
  hipMemsetAsync(den, 0, (size_t)NT*4, stream);
  hipMemsetAsync(cnt, 0, (size_t)NSEG*4, stream);
  hipMemsetAsync(bflag, 0, 4, stream);

  // counting sort of edges by (rel, dst), XCD-sharded with nt streaming reads
  int nscan = (NSEG + SCAN_ENT - 1)/SCAN_ENT;   // 129
  k_cnt<<<NSH*NCHUNK,256,0,stream>>>(eidx, cnt);
  k_scanA<<<nscan,256,0,stream>>>(cnt, bsum);
  k_scanB<<<1,256,0,stream>>>(bsum, nscan, starts);
  k_scanC<<<nscan,256,0,stream>>>(cnt, bsum, starts, startm);
  k_scatter<<<NSH*NCHUNK,256,0,stream>>>(eidx, eweight, startm, ssrc, sew);

  k_prep<<<(RREL*16384+255)/256,256,0,stream>>>(Wq,bq,Wk,bk,Ar,ur,wr,cr,bflag);

  const int attr[6] = {0,1,2,4,5,6};
  PackJobs pj{};
  int nj=0;
  auto addjob=[&](const float* s,u16* d,int ks){ pj.j[nj].src=s; pj.j[nj].dst=d; pj.j[nj].ksteps=ks; nj++; };
  addjob(W_com,pWcom,4); addjob(W_per,pWper,4);
  addjob(Wrel3,pWrel3,4); addjob(Wv,pWv,4);
  for(int r=0;r<RREL;r++) addjob(Ar + (size_t)r*16384, pAr + (size_t)r*16384, 4);
  for(int i=0;i<6;i++) addjob(Wpair + (size_t)attr[i]*32768 + 16384, pWbot + (size_t)i*16384, 4);
  dim3 pg(16, nj);
  k_pack<<<pg,256,0,stream>>>(pj);

  GArgs g{};
  // embedding GEMMs -> emb16 (bf16)
  g = GArgs{}; g.A=company; g.B=pWcom; g.M=NCY; g.rowoff=0; g.outH=emb16;
  k_gemm<0,1><<<(NCY+63)/64,256,0,stream>>>(g);
  g = GArgs{}; g.A=person; g.B=pWper; g.M=NPR; g.rowoff=NCY; g.outH=emb16;
  k_gemm<0,1><<<(NPR+63)/64,256,0,stream>>>(g);

  auto facc = [&](int r, int ebslot){   // score+acc for rel r, ebot for att slot ebslot
    FArgs f{};
    f.emb16=emb16; f.pA=pAr+(size_t)r*16384; f.rs=rs16; f.acc16=acc16; f.den=den;
    f.uvec=ur+(size_t)r*128; f.wvec=wr+(size_t)r*128; f.cr=cr+r; f.bflag=bflag; f.pri=pri+r;
    if(ebslot>=0){
      f.pB2=pWbot+(size_t)ebslot*16384; f.ebot=ebot;
      k_facc<1><<<(NT+63)/64,256,0,stream>>>(f);
    } else {
      k_facc<0><<<(NT+63)/64,256,0,stream>>>(f);
    }
  };

  // relation 3 first (bootstraps ebot for att relation 0 inside its facc)
  k_rel3s<<<NT/16,256,0,stream>>>(sew,emb16,ssrc,starts,ebot /*as t16*/);
  g = GArgs{}; g.A=ebot; g.B=pWrel3; g.M=NT; g.outH=rs16;
  k_gemm<1,0><<<(NT+63)/64,256,0,stream>>>(g);
  facc(3, 0);   // acc rel 3 + ebot for attr[0]

  for(int i=0;i<6;i++){
    int r = attr[i];
    k_edge2s<<<NT/16,256,0,stream>>>(ebot,emb16,ssrc,starts,r, rs16);
    facc(r, (i<5)? i+1 : -1);   // acc rel r + ebot for next att relation
  }

  // final: out = (acc16/den)@Wv + bv + sigmoid(skip)*gelu(emb)
  g = GArgs{}; g.A=acc16; g.B=pWv; g.M=NT;
  g.acc=out; g.den=den; g.emb16=emb16; g.bv=bvv; g.skip=skip;
  k_gemm<3,3><<<(NT+63)/64,256,0,stream>>>(g);
}

// Round 8
// 957.936 us; speedup vs baseline: 1.9545x; 1.1511x over previous
//
#include <hip/hip_runtime.h>
#include <stdint.h>

#define NCY 100000
#define NPR 50000
#define NT  150000
#define RREL 7
#define ETOT 2100000
#define EREL 300000
#define NSEG (RREL*NT)
#define NEG 0.2f

// two-pass sort geometry
#define NBUK 256
#define BWID 587            // ceil(NT/NBUK); 256*587 = 150272 >= NT
#define P1B  1024
#define CH1  2051           // ceil(ETOT/P1B); 1024*2051 >= ETOT
#define EPT  9              // ceil(CH1/256)
#define LSEG (RREL*BWID)    // 4109 local segments per bucket
#define SPT  17             // ceil(LSEG/256)

typedef __attribute__((ext_vector_type(8))) short short8;
typedef __attribute__((ext_vector_type(4))) float f32x4;
typedef unsigned short u16;

__device__ __forceinline__ float bf2f(u16 h){
  union{unsigned int u; float f;} v; v.u = ((unsigned int)h)<<16; return v.f;
}
__device__ __forceinline__ u16 f2bf(float f){
  union{unsigned int u; float f;} v; v.f=f;
  unsigned int u=v.u;
  return (u16)((u + 0x7fffu + ((u>>16)&1u))>>16);
}
__device__ __forceinline__ float lrelu(float x){ return x>0.f? x : NEG*x; }

#define MFMA(a,b,c) __builtin_amdgcn_mfma_f32_16x16x32_bf16(a,b,c,0,0,0)

// ============ pass 1: bin edges into 256 dst-range buckets, block-local ============
// Each block owns a contiguous edge chunk AND a contiguous output window ->
// every written cache line is single-block-owned (no cross-XCD ping-pong).
__global__ __launch_bounds__(256) void k_bin(const int* __restrict__ eidx,
    const float* __restrict__ ew,
    int* __restrict__ bsrc, int* __restrict__ bkey, float* __restrict__ bew,
    int* __restrict__ gcntT, int* __restrict__ poffT){
  __shared__ int cnt[NBUK];
  __shared__ int pb[NBUK];
  int blk = blockIdx.x, tid = threadIdx.x;
  int base = blk*CH1;
  int n = min(CH1, ETOT-base);
  cnt[tid]=0;
  __syncthreads();
  int esrc[EPT], ekey[EPT], erank[EPT], ebuk[EPT]; float eew[EPT];
  #pragma unroll
  for(int k=0;k<EPT;k++){
    int i = k*256 + tid;
    erank[k]=-1; esrc[k]=0; ekey[k]=0; ebuk[k]=0; eew[k]=0.f;
    if(i<n){
      int e = base+i;
      int2 sd = *(const int2*)(eidx+2*e);
      int r = e/EREL;
      int b = sd.y / BWID;
      esrc[k]=sd.x; ekey[k]=r*NT+sd.y; ebuk[k]=b; eew[k]=ew[e];
      erank[k]=atomicAdd(&cnt[b],1);
    }
  }
  __syncthreads();
  int v = cnt[tid];
  pb[tid]=v; __syncthreads();
  for(int off=1; off<256; off<<=1){
    int a=(tid>=off)?pb[tid-off]:0; __syncthreads();
    pb[tid]+=a; __syncthreads();
  }
  int excl = pb[tid]-v;
  gcntT[blk*NBUK+tid]=v;        // coalesced row write
  poffT[blk*NBUK+tid]=excl;
  pb[tid]=excl; __syncthreads();
  #pragma unroll
  for(int k=0;k<EPT;k++){
    if(erank[k]>=0){
      int pos = base + pb[ebuk[k]] + erank[k];   // within block's own window
      bsrc[pos]=esrc[k]; bkey[pos]=ekey[k]; bew[pos]=eew[k];
    }
  }
}

// bucket totals (block b sums column b) and exclusive base scan
__global__ __launch_bounds__(256) void k_bsum(const int* __restrict__ gcntT,
                                              int* __restrict__ btot){
  __shared__ int lds[256];
  int b = blockIdx.x, t = threadIdx.x;
  int s=0;
  for(int blk=t; blk<P1B; blk+=256) s += gcntT[blk*NBUK+b];
  lds[t]=s; __syncthreads();
  for(int off=128; off>0; off>>=1){ if(t<off) lds[t]+=lds[t+off]; __syncthreads(); }
  if(t==0) btot[b]=lds[0];
}

__global__ __launch_bounds__(256) void k_bscan(const int* __restrict__ btot,
                                               int* __restrict__ bbase){
  __shared__ int lds[256];
  int t=threadIdx.x;
  int v=btot[t]; lds[t]=v; __syncthreads();
  for(int off=1; off<256; off<<=1){
    int a=(t>=off)?lds[t-off]:0; __syncthreads();
    lds[t]+=a; __syncthreads();
  }
  bbase[t]=lds[t]-v;
}

// ============ pass 2: per-bucket LDS count+prefix, place into bucket region ============
__global__ __launch_bounds__(256) void k_place(
    const int* __restrict__ bsrc, const int* __restrict__ bkey, const float* __restrict__ bew,
    const int* __restrict__ gcntT, const int* __restrict__ poffT, const int* __restrict__ bbase,
    int* __restrict__ starts_g, int* __restrict__ ends_g,
    int* __restrict__ ssrc, float* __restrict__ sew){
  __shared__ int scnt[LSEG];
  __shared__ int lrun[LSEG];
  __shared__ int gofs[P1B];
  __shared__ int gl[P1B];
  __shared__ int scan[256];
  int b = blockIdx.x, t = threadIdx.x;
  int lo = b*BWID;
  int gbase = bbase[b];
  for(int i=t;i<LSEG;i+=256) scnt[i]=0;
  for(int blk=t; blk<P1B; blk+=256){
    gl[blk]   = gcntT[blk*NBUK+b];
    gofs[blk] = poffT[blk*NBUK+b];
  }
  __syncthreads();
  // count pass
  for(int blk=t; blk<P1B; blk+=256){
    int o = blk*CH1 + gofs[blk], g = gl[blk];
    for(int i=0;i<g;i++){
      int key = bkey[o+i];
      int r = key/NT; int dst = key - r*NT;
      atomicAdd(&scnt[r*BWID + (dst-lo)], 1);
    }
  }
  __syncthreads();
  // exclusive prefix over LSEG
  int ts=0;
  #pragma unroll
  for(int k=0;k<SPT;k++){ int idx=t*SPT+k; ts += (idx<LSEG)? scnt[idx]:0; }
  scan[t]=ts; __syncthreads();
  for(int off=1; off<256; off<<=1){
    int a=(t>=off)?scan[t-off]:0; __syncthreads();
    scan[t]+=a; __syncthreads();
  }
  int run = scan[t]-ts;
  #pragma unroll
  for(int k=0;k<SPT;k++){
    int idx=t*SPT+k;
    if(idx<LSEG){ lrun[idx]=run; run += scnt[idx]; }
  }
  __syncthreads();
  // global starts/ends (bucket-major positions)
  for(int idx=t; idx<LSEG; idx+=256){
    int r = idx/BWID; int ld = idx - r*BWID; int dst = lo+ld;
    if(dst<NT){
      int sgp = gbase + lrun[idx];
      starts_g[r*NT+dst] = sgp;
      ends_g[r*NT+dst]   = sgp + scnt[idx];
    }
  }
  __syncthreads();
  for(int idx=t; idx<LSEG; idx+=256) lrun[idx] += gbase;
  __syncthreads();
  // place pass: writes land in this bucket's contiguous region only
  for(int blk=t; blk<P1B; blk+=256){
    int o = blk*CH1 + gofs[blk], g = gl[blk];
    for(int i=0;i<g;i++){
      int key = bkey[o+i];
      int r = key/NT; int dst = key - r*NT;
      int pos = atomicAdd(&lrun[r*BWID+(dst-lo)], 1);
      ssrc[pos] = bsrc[o+i];
      if(r==3) sew[pos] = bew[o+i];
    }
  }
}

// ---------------- A_r = Wq_r Wk_r^T, u_r = Wq_r bk_r, w_r = Wk_r bq_r, c_r = bq.bk ----------------
__global__ __launch_bounds__(256) void k_prep(const float* __restrict__ Wq, const float* __restrict__ bq,
    const float* __restrict__ Wk, const float* __restrict__ bk,
    float* __restrict__ Ar, float* __restrict__ ur, float* __restrict__ wr,
    float* __restrict__ cr, int* __restrict__ bflag){
  int t = blockIdx.x*256 + threadIdx.x;
  if(t >= RREL*128*128) return;
  int r = t/(128*128); int ij = t - r*128*128; int i = ij>>7, j = ij&127;
  const float* wq = Wq + r*16384; const float* wk = Wk + r*16384;
  float s=0.f;
  for(int k=0;k<128;k++) s += wq[i*128+k]*wk[j*128+k];
  Ar[t] = s;
  if(i==0){
    float su=0.f, sw=0.f;
    for(int k=0;k<128;k++){ su += wq[j*128+k]*bk[r*128+k];
                            sw += wk[j*128+k]*bq[r*128+k]; }
    ur[r*128+j]=su; wr[r*128+j]=sw;
    if(j==0){
      float sc=0.f; int nz=0;
      for(int k=0;k<128;k++){ float a=bq[r*128+k], b2=bk[r*128+k];
        sc += a*b2; nz |= (a!=0.f)||(b2!=0.f); }
      cr[r]=sc; if(nz) atomicOr(bflag,1);
    }
  }
}

// ---------------- pack fp32 [K,128] matrices into bf16 MFMA B-fragment layout ----------------
struct PackJob{ const float* src; u16* dst; int ksteps; };
struct PackJobs{ PackJob j[20]; };
__global__ __launch_bounds__(256) void k_pack(PackJobs jobs){
  PackJob J = jobs.j[blockIdx.y];
  int t = blockIdx.x*256 + threadIdx.x;
  int lane = t&63, ks=(t>>6)&7, nt=t>>9;
  if(ks >= J.ksteps) return;
  int col = nt*16 + (lane&15);
  int krow = ks*32 + (lane>>4)*8;
  u16* d = J.dst + ((nt*J.ksteps + ks)*64 + lane)*8;
  for(int j=0;j<8;j++) d[j] = f2bf(J.src[(krow+j)*128 + col]);
}

// ---------------- generic [M,128] @ [128,128] MFMA GEMM with fused epilogues ----------------
struct GArgs {
  const void* A; const u16* B; int M; int rowoff;
  u16* outH; float* acc; float* den;
  const u16* emb16;
  const float* bv; const float* skip;
};

template<int EPI, int ASRC>
__global__ __launch_bounds__(256) void k_gemm(GArgs G)
{
  int wave = threadIdx.x>>6, lane = threadIdx.x&63;
  int M = G.M;
  int base = blockIdx.x*64 + wave*16;
  if(base >= M) return;
  int arow = base + (lane&15); if(arow >= M) arow = M-1;
  int kof = (lane>>4)*8;
  short8 a[4];
  if(ASRC==0){
    const u16* A = (const u16*)G.A;
    #pragma unroll
    for(int ks=0;ks<4;ks++) a[ks] = *(const short8*)(A + (size_t)arow*128 + ks*32 + kof);
  } else if(ASRC==3){
    const u16* A = (const u16*)G.A;
    float sc = 1.f/G.den[arow];
    #pragma unroll
    for(int ks=0;ks<4;ks++){
      short8 v = *(const short8*)(A + (size_t)arow*128 + ks*32 + kof);
      short8 s;
      #pragma unroll
      for(int j2=0;j2<8;j2++) s[j2]=f2bf(bf2f((u16)v[j2])*sc);
      a[ks]=s;
    }
  } else {
    const float* A = (const float*)G.A;
    #pragma unroll
    for(int ks=0;ks<4;ks++){
      const float* ap = A + (size_t)arow*128 + ks*32 + kof;
      f32x4 lo = *(const f32x4*)ap;
      f32x4 hi = *(const f32x4*)(ap+4);
      short8 s;
      #pragma unroll
      for(int j2=0;j2<4;j2++){ s[j2]=f2bf(lo[j2]); s[4+j2]=f2bf(hi[j2]); }
      a[ks]=s;
    }
  }
  f32x4 acc[8];
  #pragma unroll
  for(int nt=0;nt<8;nt++){
    f32x4 c = {0.f,0.f,0.f,0.f};
    #pragma unroll
    for(int ks=0;ks<4;ks++){
      short8 b = *(const short8*)(G.B + ((nt*4+ks)*64 + lane)*8);
      c = MFMA(a[ks], b, c);
    }
    acc[nt]=c;
  }
  int rbase = base + (lane>>4)*4;
  int cl = lane&15;
  if(EPI==0){
    #pragma unroll
    for(int nt=0;nt<8;nt++)
      for(int j=0;j<4;j++){
        int row=rbase+j;
        if(row<M){
          int col=nt*16+cl;
          G.outH[(size_t)(G.rowoff+row)*128+col] = f2bf(acc[nt][j]);
        }
      }
  } else if(EPI==1){
    #pragma unroll
    for(int nt=0;nt<8;nt++)
      for(int j=0;j<4;j++){
        int row=rbase+j;
        if(row<M){
          int col=nt*16+cl;
          G.outH[(size_t)row*128+col]=f2bf(lrelu(acc[nt][j]));
        }
      }
  } else { // EPI==3
    float sg = 1.f/(1.f+__expf(-G.skip[0]));
    #pragma unroll
    for(int nt=0;nt<8;nt++)
      for(int j=0;j<4;j++){
        int row=rbase+j;
        if(row<M){
          int col=nt*16+cl;
          float x = bf2f(G.emb16[(size_t)row*128+col]);
          float g = 0.5f*x*(1.f+erff(x*0.70710678118f));
          G.acc[(size_t)row*128+col] = acc[nt][j] + G.bv[col] + sg*g;
        }
      }
  }
}

// -------- fused per-relation: score+accumulate + optional ebot for NEXT relation --------
struct FArgs {
  const u16* emb16; const u16* pA; const u16* pB2;
  const u16* rs; u16* acc16; float* den; u16* ebot;
  const float* uvec; const float* wvec; const float* cr; const int* bflag; const float* pri;
};

template<int HAS_EBOT>
__global__ __launch_bounds__(256) void k_facc(FArgs F)
{
  int wave = threadIdx.x>>6, lane = threadIdx.x&63;
  int base = blockIdx.x*64 + wave*16;
  if(base >= NT) return;
  int arow = base + (lane&15); if(arow >= NT) arow = NT-1;
  int kof = (lane>>4)*8;
  short8 a[4];
  #pragma unroll
  for(int ks=0;ks<4;ks++) a[ks] = *(const short8*)(F.emb16 + (size_t)arow*128 + ks*32 + kof);
  int rbase = base + (lane>>4)*4;
  int cl = lane&15;
  if(HAS_EBOT){
    #pragma unroll
    for(int nt=0;nt<8;nt++){
      f32x4 c = {0.f,0.f,0.f,0.f};
      #pragma unroll
      for(int ks=0;ks<4;ks++){
        short8 b = *(const short8*)(F.pB2 + ((nt*4+ks)*64 + lane)*8);
        c = MFMA(a[ks], b, c);
      }
      #pragma unroll
      for(int j=0;j<4;j++){
        int row=rbase+j;
        if(row<NT) F.ebot[(size_t)row*128 + nt*16+cl] = f2bf(__expf(c[j]));
      }
    }
  }
  f32x4 accS[8];
  #pragma unroll
  for(int nt=0;nt<8;nt++){
    f32x4 c = {0.f,0.f,0.f,0.f};
    #pragma unroll
    for(int ks=0;ks<4;ks++){
      short8 b = *(const short8*)(F.pA + ((nt*4+ks)*64 + lane)*8);
      c = MFMA(a[ks], b, c);
    }
    accS[nt]=c;
  }
  float prival = F.pri[0] * 0.08838834764831845f;
  int bias = *F.bflag;
  float rsv[4][8];
  #pragma unroll
  for(int j=0;j<4;j++){
    int row=rbase+j; bool ok = row<NT;
    #pragma unroll
    for(int nt=0;nt<8;nt++){
      int col=nt*16+cl;
      rsv[j][nt] = ok ? bf2f(F.rs[(size_t)row*128+col]) : 0.f;
    }
  }
  #pragma unroll
  for(int j=0;j<4;j++){
    int row=rbase+j; bool ok = row<NT;
    float p=0.f;
    if(ok){
      #pragma unroll
      for(int nt=0;nt<8;nt++) p += accS[nt][j]*rsv[j][nt];
      if(bias){
        #pragma unroll
        for(int nt=0;nt<8;nt++){
          int col=nt*16+cl;
          p += bf2f(F.emb16[(size_t)row*128+col])*F.uvec[col]
             + rsv[j][nt]*F.wvec[col];
        }
      }
    }
    p += __shfl_xor(p,1,16); p += __shfl_xor(p,2,16);
    p += __shfl_xor(p,4,16); p += __shfl_xor(p,8,16);
    float e = __expf((p + F.cr[0])*prival);
    if(ok){
      #pragma unroll
      for(int nt=0;nt<8;nt++){
        size_t o=(size_t)row*128 + nt*16+cl;
        F.acc16[o] = f2bf(bf2f(F.acc16[o]) + e*rsv[j][nt]);
      }
      if(cl==0) F.den[row] += e;
    }
  }
}

// ------- per-dst combine: rs = lrelu( sum(x_j*ev_j)/sum(ev_j) ), ev_j = ebot[src_j] -------
__global__ __launch_bounds__(256) void k_edge2s(const u16* __restrict__ ebot,
    const u16* __restrict__ emb16, const int* __restrict__ ssrc,
    const int* __restrict__ starts_g, const int* __restrict__ ends_g, int rel,
    u16* __restrict__ rsout){
  int n = blockIdx.x*16 + (threadIdx.x>>4);
  int dof = (threadIdx.x&15)*8;
  int s = starts_g[rel*NT + n];
  int e_end = ends_g[rel*NT + n];
  float num[8]={0,0,0,0,0,0,0,0}, den[8]={0,0,0,0,0,0,0,0};
  int p = s;
  for(; p+1 < e_end; p += 2){
    int s0 = ssrc[p], s1 = ssrc[p+1];
    short8 ev0 = *(const short8*)(ebot  + (size_t)s0*128 + dof);
    short8 xj0 = *(const short8*)(emb16 + (size_t)s0*128 + dof);
    short8 ev1 = *(const short8*)(ebot  + (size_t)s1*128 + dof);
    short8 xj1 = *(const short8*)(emb16 + (size_t)s1*128 + dof);
    #pragma unroll
    for(int j=0;j<8;j++){
      float e0 = bf2f((u16)ev0[j]), e1 = bf2f((u16)ev1[j]);
      num[j] += bf2f((u16)xj0[j])*e0 + bf2f((u16)xj1[j])*e1;
      den[j] += e0 + e1;
    }
  }
  if(p < e_end){
    int s0 = ssrc[p];
    short8 ev0 = *(const short8*)(ebot  + (size_t)s0*128 + dof);
    short8 xj0 = *(const short8*)(emb16 + (size_t)s0*128 + dof);
    #pragma unroll
    for(int j=0;j<8;j++){
      float e0 = bf2f((u16)ev0[j]);
      num[j] += bf2f((u16)xj0[j])*e0;
      den[j] += e0;
    }
  }
  u16 o8[8];
  #pragma unroll
  for(int j=0;j<8;j++) o8[j] = f2bf(lrelu(num[j]/(den[j]+1e-16f)));
  *(short8*)(rsout + (size_t)n*128 + dof) = *(short8*)o8;
}

// ------- relation 3: t = sum(exp(w)*x_j)/sum(exp(w)) -------
__global__ __launch_bounds__(256) void k_rel3s(const float* __restrict__ sew,
    const u16* __restrict__ emb16, const int* __restrict__ ssrc,
    const int* __restrict__ starts_g, const int* __restrict__ ends_g,
    u16* __restrict__ t16){
  int n = blockIdx.x*16 + (threadIdx.x>>4);
  int dof = (threadIdx.x&15)*8;
  int s = starts_g[3*NT + n];
  int e_end = ends_g[3*NT + n];
  float num[8]={0,0,0,0,0,0,0,0}, den=0.f;
  for(int p=s; p<e_end; p++){
    int src = ssrc[p];
    float wv = __expf(sew[p]);
    den += wv;
    short8 xj8 = *(const short8*)(emb16 + (size_t)src*128 + dof);
    #pragma unroll
    for(int j=0;j<8;j++) num[j] += wv*bf2f((u16)xj8[j]);
  }
  float inv = 1.f/(den+1e-16f);
  u16 o8[8];
  #pragma unroll
  for(int j=0;j<8;j++) o8[j] = f2bf(num[j]*inv);
  *(short8*)(t16 + (size_t)n*128 + dof) = *(short8*)o8;
}

extern "C" void kernel_launch(void* const* d_in, const int* in_sizes, int n_in,
                              void* d_out, int out_size, void* d_ws, size_t ws_size,
                              hipStream_t stream){
  const float* company = (const float*)d_in[0];
  const float* person  = (const float*)d_in[1];
  const float* eweight = (const float*)d_in[2];
  const float* W_com   = (const float*)d_in[3];
  const float* W_per   = (const float*)d_in[4];
  const float* Wq      = (const float*)d_in[5];
  const float* bq      = (const float*)d_in[6];
  const float* Wk      = (const float*)d_in[7];
  const float* bk      = (const float*)d_in[8];
  const float* Wv      = (const float*)d_in[9];
  const float* bvv     = (const float*)d_in[10];
  const float* pri     = (const float*)d_in[11];
  const float* Wpair   = (const float*)d_in[12];
  const float* Wrel3   = (const float*)d_in[13];
  const float* skip    = (const float*)d_in[14];
  const int*   eidx    = (const int*)d_in[15];
  float* out = (float*)d_out;

  // workspace (~181 MB)
  char* w = (char*)d_ws;
  auto alloc = [&](size_t sz)->void*{ void* p=(void*)w; w += (sz+255)&~(size_t)255; return p; };
  u16*   emb16 = (u16*)alloc((size_t)NT*128*2);        // 38.4 MB
  u16*   ebot  = (u16*)alloc((size_t)NT*128*2);        // 38.4 MB
  u16*   rs16  = (u16*)alloc((size_t)NT*128*2);        // 38.4 MB (aliases sort bsrc/bkey/bew)
  u16*   acc16 = (u16*)alloc((size_t)NT*128*2);        // 38.4 MB (aliases gcntT/poffT/btot/bbase)
  float* den   = (float*)alloc((size_t)NT*4);
  int*   starts_g = (int*)alloc((size_t)NSEG*4);       // 4.2 MB
  int*   ends_g   = (int*)alloc((size_t)NSEG*4);       // 4.2 MB
  int*   ssrc  = (int*)alloc((size_t)ETOT*4);          // 8.4 MB
  float* sew   = (float*)alloc((size_t)ETOT*4);        // 8.4 MB
  float* Ar    = (float*)alloc((size_t)RREL*16384*4);
  float* ur    = (float*)alloc(RREL*128*4);
  float* wr    = (float*)alloc(RREL*128*4);
  float* cr    = (float*)alloc(RREL*4);
  int*   bflag = (int*)alloc(256);
  u16* pWcom  = (u16*)alloc(16384*2);
  u16* pWper  = (u16*)alloc(16384*2);
  u16* pWrel3 = (u16*)alloc(16384*2);
  u16* pWv    = (u16*)alloc(16384*2);
  u16* pAr    = (u16*)alloc((size_t)RREL*16384*2);
  u16* pWbot  = (u16*)alloc((size_t)6*16384*2);
  (void)ws_size; (void)in_sizes; (void)n_in; (void)out_size;

  // sort temporaries alias dead regions (rs16/acc16 written only after sort)
  int*   bsrc  = (int*)rs16;
  int*   bkey  = bsrc + ETOT;
  float* bew   = (float*)(bkey + ETOT);                // 25.2 MB <= 38.4 ✓
  int*   gcntT = (int*)acc16;                          // 1 MB
  int*   poffT = gcntT + P1B*NBUK;                     // 1 MB
  int*   btot  = poffT + P1B*NBUK;
  int*   bbase = btot + NBUK;

  hipMemsetAsync(den, 0, (size_t)NT*4, stream);
  hipMemsetAsync(bflag, 0, 4, stream);

  // two-pass counting sort by (rel, dst), bucket-major layout
  k_bin<<<P1B,256,0,stream>>>(eidx, eweight, bsrc, bkey, bew, gcntT, poffT);
  k_bsum<<<NBUK,256,0,stream>>>(gcntT, btot);
  k_bscan<<<1,256,0,stream>>>(btot, bbase);
  k_place<<<NBUK,256,0,stream>>>(bsrc,bkey,bew,gcntT,poffT,bbase,
                                 starts_g,ends_g,ssrc,sew);
  hipMemsetAsync(acc16, 0, (size_t)NT*128*2, stream);  // after sort (aliased)

  k_prep<<<(RREL*16384+255)/256,256,0,stream>>>(Wq,bq,Wk,bk,Ar,ur,wr,cr,bflag);

  const int attr[6] = {0,1,2,4,5,6};
  PackJobs pj{};
  int nj=0;
  auto addjob=[&](const float* s,u16* d,int ks){ pj.j[nj].src=s; pj.j[nj].dst=d; pj.j[nj].ksteps=ks; nj++; };
  addjob(W_com,pWcom,4); addjob(W_per,pWper,4);
  addjob(Wrel3,pWrel3,4); addjob(Wv,pWv,4);
  for(int r=0;r<RREL;r++) addjob(Ar + (size_t)r*16384, pAr + (size_t)r*16384, 4);
  for(int i=0;i<6;i++) addjob(Wpair + (size_t)attr[i]*32768 + 16384, pWbot + (size_t)i*16384, 4);
  dim3 pg(16, nj);
  k_pack<<<pg,256,0,stream>>>(pj);

  GArgs g{};
  g = GArgs{}; g.A=company; g.B=pWcom; g.M=NCY; g.rowoff=0; g.outH=emb16;
  k_gemm<0,1><<<(NCY+63)/64,256,0,stream>>>(g);
  g = GArgs{}; g.A=person; g.B=pWper; g.M=NPR; g.rowoff=NCY; g.outH=emb16;
  k_gemm<0,1><<<(NPR+63)/64,256,0,stream>>>(g);

  auto facc = [&](int r, int ebslot){
    FArgs f{};
    f.emb16=emb16; f.pA=pAr+(size_t)r*16384; f.rs=rs16; f.acc16=acc16; f.den=den;
    f.uvec=ur+(size_t)r*128; f.wvec=wr+(size_t)r*128; f.cr=cr+r; f.bflag=bflag; f.pri=pri+r;
    if(ebslot>=0){
      f.pB2=pWbot+(size_t)ebslot*16384; f.ebot=ebot;
      k_facc<1><<<(NT+63)/64,256,0,stream>>>(f);
    } else {
      k_facc<0><<<(NT+63)/64,256,0,stream>>>(f);
    }
  };

  // relation 3 first (bootstraps ebot for att relation 0)
  k_rel3s<<<NT/16,256,0,stream>>>(sew,emb16,ssrc,starts_g,ends_g,ebot);
  g = GArgs{}; g.A=ebot; g.B=pWrel3; g.M=NT; g.outH=rs16;
  k_gemm<1,0><<<(NT+63)/64,256,0,stream>>>(g);
  facc(3, 0);

  for(int i=0;i<6;i++){
    int r = attr[i];
    k_edge2s<<<NT/16,256,0,stream>>>(ebot,emb16,ssrc,starts_g,ends_g,r, rs16);
    facc(r, (i<5)? i+1 : -1);
  }

  // final: out = (acc16/den)@Wv + bv + sigmoid(skip)*gelu(emb)
  g = GArgs{}; g.A=acc16; g.B=pWv; g.M=NT;
  g.acc=out; g.den=den; g.emb16=emb16; g.bv=bvv; g.skip=skip;
  k_gemm<3,3><<<(NT+63)/64,256,0,stream>>>(g);
}

// Round 9
// 904.904 us; speedup vs baseline: 2.0691x; 1.0586x over previous
//
#include <hip/hip_runtime.h>
#include <stdint.h>

#define NCY 100000
#define NPR 50000
#define NT  150000
#define RREL 7
#define ETOT 2100000
#define EREL 300000
#define NSEG (RREL*NT)
#define NEG 0.2f

// two-pass sort geometry
#define NBUK 256
#define BWID 587
#define P1B  1024
#define CH1  2051
#define EPT  9
#define LSEG (RREL*BWID)
#define SPT  17

#define LSTR 136      // LDS row stride (u16) for rs tiles

typedef __attribute__((ext_vector_type(8))) short short8;
typedef __attribute__((ext_vector_type(4))) float f32x4;
typedef unsigned short u16;

__device__ __forceinline__ float bf2f(u16 h){
  union{unsigned int u; float f;} v; v.u = ((unsigned int)h)<<16; return v.f;
}
__device__ __forceinline__ u16 f2bf(float f){
  union{unsigned int u; float f;} v; v.f=f;
  unsigned int u=v.u;
  return (u16)((u + 0x7fffu + ((u>>16)&1u))>>16);
}
__device__ __forceinline__ float lrelu(float x){ return x>0.f? x : NEG*x; }

#define MFMA(a,b,c) __builtin_amdgcn_mfma_f32_16x16x32_bf16(a,b,c,0,0,0)

// ============ two-pass counting sort (round-8 proven) ============
__global__ __launch_bounds__(256) void k_bin(const int* __restrict__ eidx,
    const float* __restrict__ ew,
    int* __restrict__ bsrc, int* __restrict__ bkey, float* __restrict__ bew,
    int* __restrict__ gcntT, int* __restrict__ poffT){
  __shared__ int cnt[NBUK];
  __shared__ int pb[NBUK];
  int blk = blockIdx.x, tid = threadIdx.x;
  int base = blk*CH1;
  int n = min(CH1, ETOT-base);
  cnt[tid]=0;
  __syncthreads();
  int esrc[EPT], ekey[EPT], erank[EPT], ebuk[EPT]; float eew[EPT];
  #pragma unroll
  for(int k=0;k<EPT;k++){
    int i = k*256 + tid;
    erank[k]=-1; esrc[k]=0; ekey[k]=0; ebuk[k]=0; eew[k]=0.f;
    if(i<n){
      int e = base+i;
      int2 sd = *(const int2*)(eidx+2*e);
      int r = e/EREL;
      int b = sd.y / BWID;
      esrc[k]=sd.x; ekey[k]=r*NT+sd.y; ebuk[k]=b; eew[k]=ew[e];
      erank[k]=atomicAdd(&cnt[b],1);
    }
  }
  __syncthreads();
  int v = cnt[tid];
  pb[tid]=v; __syncthreads();
  for(int off=1; off<256; off<<=1){
    int a=(tid>=off)?pb[tid-off]:0; __syncthreads();
    pb[tid]+=a; __syncthreads();
  }
  int excl = pb[tid]-v;
  gcntT[blk*NBUK+tid]=v;
  poffT[blk*NBUK+tid]=excl;
  pb[tid]=excl; __syncthreads();
  #pragma unroll
  for(int k=0;k<EPT;k++){
    if(erank[k]>=0){
      int pos = base + pb[ebuk[k]] + erank[k];
      bsrc[pos]=esrc[k]; bkey[pos]=ekey[k]; bew[pos]=eew[k];
    }
  }
}

__global__ __launch_bounds__(256) void k_bsum(const int* __restrict__ gcntT,
                                              int* __restrict__ btot){
  __shared__ int lds[256];
  int b = blockIdx.x, t = threadIdx.x;
  int s=0;
  for(int blk=t; blk<P1B; blk+=256) s += gcntT[blk*NBUK+b];
  lds[t]=s; __syncthreads();
  for(int off=128; off>0; off>>=1){ if(t<off) lds[t]+=lds[t+off]; __syncthreads(); }
  if(t==0) btot[b]=lds[0];
}

__global__ __launch_bounds__(256) void k_bscan(const int* __restrict__ btot,
                                               int* __restrict__ bbase){
  __shared__ int lds[256];
  int t=threadIdx.x;
  int v=btot[t]; lds[t]=v; __syncthreads();
  for(int off=1; off<256; off<<=1){
    int a=(t>=off)?lds[t-off]:0; __syncthreads();
    lds[t]+=a; __syncthreads();
  }
  bbase[t]=lds[t]-v;
}

__global__ __launch_bounds__(256) void k_place(
    const int* __restrict__ bsrc, const int* __restrict__ bkey, const float* __restrict__ bew,
    const int* __restrict__ gcntT, const int* __restrict__ poffT, const int* __restrict__ bbase,
    int* __restrict__ starts_g, int* __restrict__ ends_g,
    int* __restrict__ ssrc, float* __restrict__ sew){
  __shared__ int scnt[LSEG];
  __shared__ int lrun[LSEG];
  __shared__ int gofs[P1B];
  __shared__ int gl[P1B];
  __shared__ int scan[256];
  int b = blockIdx.x, t = threadIdx.x;
  int lo = b*BWID;
  int gbase = bbase[b];
  for(int i=t;i<LSEG;i+=256) scnt[i]=0;
  for(int blk=t; blk<P1B; blk+=256){
    gl[blk]   = gcntT[blk*NBUK+b];
    gofs[blk] = poffT[blk*NBUK+b];
  }
  __syncthreads();
  for(int blk=t; blk<P1B; blk+=256){
    int o = blk*CH1 + gofs[blk], g = gl[blk];
    for(int i=0;i<g;i++){
      int key = bkey[o+i];
      int r = key/NT; int dst = key - r*NT;
      atomicAdd(&scnt[r*BWID + (dst-lo)], 1);
    }
  }
  __syncthreads();
  int ts=0;
  #pragma unroll
  for(int k=0;k<SPT;k++){ int idx=t*SPT+k; ts += (idx<LSEG)? scnt[idx]:0; }
  scan[t]=ts; __syncthreads();
  for(int off=1; off<256; off<<=1){
    int a=(t>=off)?scan[t-off]:0; __syncthreads();
    scan[t]+=a; __syncthreads();
  }
  int run = scan[t]-ts;
  #pragma unroll
  for(int k=0;k<SPT;k++){
    int idx=t*SPT+k;
    if(idx<LSEG){ lrun[idx]=run; run += scnt[idx]; }
  }
  __syncthreads();
  for(int idx=t; idx<LSEG; idx+=256){
    int r = idx/BWID; int ld = idx - r*BWID; int dst = lo+ld;
    if(dst<NT){
      int sgp = gbase + lrun[idx];
      starts_g[r*NT+dst] = sgp;
      ends_g[r*NT+dst]   = sgp + scnt[idx];
    }
  }
  __syncthreads();
  for(int idx=t; idx<LSEG; idx+=256) lrun[idx] += gbase;
  __syncthreads();
  for(int blk=t; blk<P1B; blk+=256){
    int o = blk*CH1 + gofs[blk], g = gl[blk];
    for(int i=0;i<g;i++){
      int key = bkey[o+i];
      int r = key/NT; int dst = key - r*NT;
      int pos = atomicAdd(&lrun[r*BWID+(dst-lo)], 1);
      ssrc[pos] = bsrc[o+i];
      if(r==3) sew[pos] = bew[o+i];
    }
  }
}

// ---------------- A_r = Wq_r Wk_r^T etc ----------------
__global__ __launch_bounds__(256) void k_prep(const float* __restrict__ Wq, const float* __restrict__ bq,
    const float* __restrict__ Wk, const float* __restrict__ bk,
    float* __restrict__ Ar, float* __restrict__ ur, float* __restrict__ wr,
    float* __restrict__ cr, int* __restrict__ bflag){
  int t = blockIdx.x*256 + threadIdx.x;
  if(t >= RREL*128*128) return;
  int r = t/(128*128); int ij = t - r*128*128; int i = ij>>7, j = ij&127;
  const float* wq = Wq + r*16384; const float* wk = Wk + r*16384;
  float s=0.f;
  for(int k=0;k<128;k++) s += wq[i*128+k]*wk[j*128+k];
  Ar[t] = s;
  if(i==0){
    float su=0.f, sw=0.f;
    for(int k=0;k<128;k++){ su += wq[j*128+k]*bk[r*128+k];
                            sw += wk[j*128+k]*bq[r*128+k]; }
    ur[r*128+j]=su; wr[r*128+j]=sw;
    if(j==0){
      float sc=0.f; int nz=0;
      for(int k=0;k<128;k++){ float a=bq[r*128+k], b2=bk[r*128+k];
        sc += a*b2; nz |= (a!=0.f)||(b2!=0.f); }
      cr[r]=sc; if(nz) atomicOr(bflag,1);
    }
  }
}

// ---------------- pack fp32 [K,128] into bf16 MFMA B-fragment layout ----------------
struct PackJob{ const float* src; u16* dst; int ksteps; };
struct PackJobs{ PackJob j[20]; };
__global__ __launch_bounds__(256) void k_pack(PackJobs jobs){
  PackJob J = jobs.j[blockIdx.y];
  int t = blockIdx.x*256 + threadIdx.x;
  int lane = t&63, ks=(t>>6)&7, nt=t>>9;
  if(ks >= J.ksteps) return;
  int col = nt*16 + (lane&15);
  int krow = ks*32 + (lane>>4)*8;
  u16* d = J.dst + ((nt*J.ksteps + ks)*64 + lane)*8;
  for(int j=0;j<8;j++) d[j] = f2bf(J.src[(krow+j)*128 + col]);
}

// ---------------- generic GEMM: EPI 0 emb->bf16, EPI 4 exp->bf16, EPI 3 final ----------------
struct GArgs {
  const void* A; const u16* B; int M; int rowoff;
  u16* outH; float* acc; float* den;
  const u16* emb16;
  const float* bv; const float* skip;
};

template<int EPI, int ASRC>
__global__ __launch_bounds__(256) void k_gemm(GArgs G)
{
  int wave = threadIdx.x>>6, lane = threadIdx.x&63;
  int M = G.M;
  int base = blockIdx.x*64 + wave*16;
  if(base >= M) return;
  int arow = base + (lane&15); if(arow >= M) arow = M-1;
  int kof = (lane>>4)*8;
  short8 a[4];
  if(ASRC==0){
    const u16* A = (const u16*)G.A;
    #pragma unroll
    for(int ks=0;ks<4;ks++) a[ks] = *(const short8*)(A + (size_t)arow*128 + ks*32 + kof);
  } else if(ASRC==3){
    const u16* A = (const u16*)G.A;
    float sc = 1.f/G.den[arow];
    #pragma unroll
    for(int ks=0;ks<4;ks++){
      short8 v = *(const short8*)(A + (size_t)arow*128 + ks*32 + kof);
      short8 s;
      #pragma unroll
      for(int j2=0;j2<8;j2++) s[j2]=f2bf(bf2f((u16)v[j2])*sc);
      a[ks]=s;
    }
  } else {
    const float* A = (const float*)G.A;
    #pragma unroll
    for(int ks=0;ks<4;ks++){
      const float* ap = A + (size_t)arow*128 + ks*32 + kof;
      f32x4 lo = *(const f32x4*)ap;
      f32x4 hi = *(const f32x4*)(ap+4);
      short8 s;
      #pragma unroll
      for(int j2=0;j2<4;j2++){ s[j2]=f2bf(lo[j2]); s[4+j2]=f2bf(hi[j2]); }
      a[ks]=s;
    }
  }
  f32x4 acc[8];
  #pragma unroll
  for(int nt=0;nt<8;nt++){
    f32x4 c = {0.f,0.f,0.f,0.f};
    #pragma unroll
    for(int ks=0;ks<4;ks++){
      short8 b = *(const short8*)(G.B + ((nt*4+ks)*64 + lane)*8);
      c = MFMA(a[ks], b, c);
    }
    acc[nt]=c;
  }
  int rbase = base + (lane>>4)*4;
  int cl = lane&15;
  if(EPI==0){
    #pragma unroll
    for(int nt=0;nt<8;nt++)
      for(int j=0;j<4;j++){
        int row=rbase+j;
        if(row<M){
          int col=nt*16+cl;
          G.outH[(size_t)(G.rowoff+row)*128+col] = f2bf(acc[nt][j]);
        }
      }
  } else if(EPI==4){
    #pragma unroll
    for(int nt=0;nt<8;nt++)
      for(int j=0;j<4;j++){
        int row=rbase+j;
        if(row<M){
          int col=nt*16+cl;
          G.outH[(size_t)row*128+col]=f2bf(__expf(acc[nt][j]));
        }
      }
  } else { // EPI==3
    float sg = 1.f/(1.f+__expf(-G.skip[0]));
    #pragma unroll
    for(int nt=0;nt<8;nt++)
      for(int j=0;j<4;j++){
        int row=rbase+j;
        if(row<M){
          int col=nt*16+cl;
          float x = bf2f(G.emb16[(size_t)row*128+col]);
          float g = 0.5f*x*(1.f+erff(x*0.70710678118f));
          G.acc[(size_t)row*128+col] = acc[nt][j] + G.bv[col] + sg*g;
        }
      }
  }
}

// ================= fused pair kernels =================
struct PArgs {
  const u16* emb16; const int* ssrc; const int* starts_g; const int* ends_g;
  const float* sew;
  const u16* ebR1; const u16* ebR2;    // gather sources
  const u16* pA1; const u16* pA2;      // score matrices
  const u16* pWr3;                     // fp0 only
  const u16* pB2a; const u16* pB2b; u16* ebW1; u16* ebW2;
  u16* acc16; float* den;
  const float* u1; const float* w1; const float* c1; const float* p1;
  const float* u2; const float* w2; const float* c2; const float* p2;
  const int* bflag;
  int r1, r2;
};

// gather one att relation's rs rows for this block into LDS [64][LSTR]
__device__ __forceinline__ void gatherAtt(u16* buf, const u16* __restrict__ ebt,
    const u16* __restrict__ emb16, const int* __restrict__ ssrc,
    const int* __restrict__ sg, const int* __restrict__ eg,
    int rel, int base64, int tid){
  #pragma unroll
  for(int p2=0;p2<2;p2++){
    int ln = (tid>>3) + p2*32;
    int gn = base64 + ln;
    int cb = (tid&7)*16;
    float num[16]={0,0,0,0,0,0,0,0,0,0,0,0,0,0,0,0};
    float den[16]={0,0,0,0,0,0,0,0,0,0,0,0,0,0,0,0};
    if(gn<NT){
      int s=sg[rel*NT+gn], e=eg[rel*NT+gn];
      for(int pos=s;pos<e;pos++){
        int src=ssrc[pos];
        const u16* eb=ebt+(size_t)src*128+cb;
        const u16* xm=emb16+(size_t)src*128+cb;
        short8 e0=*(const short8*)eb, e1=*(const short8*)(eb+8);
        short8 x0=*(const short8*)xm, x1=*(const short8*)(xm+8);
        #pragma unroll
        for(int j=0;j<8;j++){
          float ev0=bf2f((u16)e0[j]), ev1=bf2f((u16)e1[j]);
          num[j]   += bf2f((u16)x0[j])*ev0; den[j]   += ev0;
          num[8+j] += bf2f((u16)x1[j])*ev1; den[8+j] += ev1;
        }
      }
    }
    #pragma unroll
    for(int j=0;j<16;j++) buf[ln*LSTR+cb+j] = f2bf(lrelu(num[j]/(den[j]+1e-16f)));
  }
}

// gather rel-3 weighted mean t into LDS (no lrelu)
__device__ __forceinline__ void gatherR3(u16* buf, const float* __restrict__ sew,
    const u16* __restrict__ emb16, const int* __restrict__ ssrc,
    const int* __restrict__ sg, const int* __restrict__ eg,
    int base64, int tid){
  #pragma unroll
  for(int p2=0;p2<2;p2++){
    int ln = (tid>>3) + p2*32;
    int gn = base64 + ln;
    int cb = (tid&7)*16;
    float num[16]={0,0,0,0,0,0,0,0,0,0,0,0,0,0,0,0};
    float dn=0.f;
    if(gn<NT){
      int s=sg[3*NT+gn], e=eg[3*NT+gn];
      for(int pos=s;pos<e;pos++){
        int src=ssrc[pos];
        float wv=__expf(sew[pos]);
        dn += wv;
        const u16* xm=emb16+(size_t)src*128+cb;
        short8 x0=*(const short8*)xm, x1=*(const short8*)(xm+8);
        #pragma unroll
        for(int j=0;j<8;j++){
          num[j]   += wv*bf2f((u16)x0[j]);
          num[8+j] += wv*bf2f((u16)x1[j]);
        }
      }
    }
    float inv=1.f/(dn+1e-16f);
    #pragma unroll
    for(int j=0;j<16;j++) buf[ln*LSTR+cb+j] = f2bf(num[j]*inv);
  }
}

// generic fused pair kernel (att relations). NR = #relations (1 or 2), NEB = #ebot emits.
template<int NR, int NEB>
__global__ __launch_bounds__(256) void k_fp(PArgs P)
{
  __shared__ u16 lds1[64*LSTR];
  __shared__ u16 lds2[64*LSTR];
  int tid = threadIdx.x;
  int base64 = blockIdx.x*64;
  gatherAtt(lds1, P.ebR1, P.emb16, P.ssrc, P.starts_g, P.ends_g, P.r1, base64, tid);
  if(NR==2) gatherAtt(lds2, P.ebR2, P.emb16, P.ssrc, P.starts_g, P.ends_g, P.r2, base64, tid);
  __syncthreads();
  int wave=tid>>6, lane=tid&63;
  int base = base64 + wave*16;
  if(base >= NT) return;
  int arow = base + (lane&15); if(arow >= NT) arow = NT-1;
  int kof = (lane>>4)*8;
  short8 a[4];
  #pragma unroll
  for(int ks=0;ks<4;ks++) a[ks] = *(const short8*)(P.emb16 + (size_t)arow*128 + ks*32 + kof);
  int rbase = base + (lane>>4)*4;
  int lrb   = wave*16 + (lane>>4)*4;
  int cl = lane&15;
  int bias = *P.bflag;
  float e1v[4], e2v[4];
  // --- score r1 ---
  {
    f32x4 accS[8];
    #pragma unroll
    for(int nt=0;nt<8;nt++){
      f32x4 c = {0.f,0.f,0.f,0.f};
      #pragma unroll
      for(int ks=0;ks<4;ks++){
        short8 b = *(const short8*)(P.pA1 + ((nt*4+ks)*64 + lane)*8);
        c = MFMA(a[ks], b, c);
      }
      accS[nt]=c;
    }
    float prival = P.p1[0]*0.08838834764831845f;
    #pragma unroll
    for(int j=0;j<4;j++){
      int row=rbase+j; bool ok=row<NT;
      float p=0.f;
      if(ok){
        #pragma unroll
        for(int nt=0;nt<8;nt++){
          int col=nt*16+cl;
          float rv = bf2f(lds1[(lrb+j)*LSTR+col]);
          p += accS[nt][j]*rv;
          if(bias) p += bf2f(P.emb16[(size_t)row*128+col])*P.u1[col] + rv*P.w1[col];
        }
      }
      p += __shfl_xor(p,1,16); p += __shfl_xor(p,2,16);
      p += __shfl_xor(p,4,16); p += __shfl_xor(p,8,16);
      e1v[j] = __expf((p + P.c1[0])*prival);
    }
  }
  // --- score r2 ---
  if(NR==2){
    f32x4 accS[8];
    #pragma unroll
    for(int nt=0;nt<8;nt++){
      f32x4 c = {0.f,0.f,0.f,0.f};
      #pragma unroll
      for(int ks=0;ks<4;ks++){
        short8 b = *(const short8*)(P.pA2 + ((nt*4+ks)*64 + lane)*8);
        c = MFMA(a[ks], b, c);
      }
      accS[nt]=c;
    }
    float prival = P.p2[0]*0.08838834764831845f;
    #pragma unroll
    for(int j=0;j<4;j++){
      int row=rbase+j; bool ok=row<NT;
      float p=0.f;
      if(ok){
        #pragma unroll
        for(int nt=0;nt<8;nt++){
          int col=nt*16+cl;
          float rv = bf2f(lds2[(lrb+j)*LSTR+col]);
          p += accS[nt][j]*rv;
          if(bias) p += bf2f(P.emb16[(size_t)row*128+col])*P.u2[col] + rv*P.w2[col];
        }
      }
      p += __shfl_xor(p,1,16); p += __shfl_xor(p,2,16);
      p += __shfl_xor(p,4,16); p += __shfl_xor(p,8,16);
      e2v[j] = __expf((p + P.c2[0])*prival);
    }
  }
  // --- single RMW accumulate ---
  #pragma unroll
  for(int j=0;j<4;j++){
    int row=rbase+j;
    if(row<NT){
      float ee1=e1v[j];
      float ee2=(NR==2)? e2v[j] : 0.f;
      #pragma unroll
      for(int nt=0;nt<8;nt++){
        int col=nt*16+cl;
        size_t o=(size_t)row*128+col;
        float add = ee1*bf2f(lds1[(lrb+j)*LSTR+col]);
        if(NR==2) add += ee2*bf2f(lds2[(lrb+j)*LSTR+col]);
        P.acc16[o] = f2bf(bf2f(P.acc16[o]) + add);
      }
      if(cl==0) P.den[row] += ee1 + ee2;
    }
  }
  // --- emit next ebot tables ---
  if(NEB>=1){
    #pragma unroll
    for(int nt=0;nt<8;nt++){
      f32x4 c = {0.f,0.f,0.f,0.f};
      #pragma unroll
      for(int ks=0;ks<4;ks++){
        short8 b = *(const short8*)(P.pB2a + ((nt*4+ks)*64 + lane)*8);
        c = MFMA(a[ks], b, c);
      }
      #pragma unroll
      for(int j=0;j<4;j++){
        int row=rbase+j;
        if(row<NT) P.ebW1[(size_t)row*128 + nt*16+cl] = f2bf(__expf(c[j]));
      }
    }
  }
  if(NEB>=2){
    #pragma unroll
    for(int nt=0;nt<8;nt++){
      f32x4 c = {0.f,0.f,0.f,0.f};
      #pragma unroll
      for(int ks=0;ks<4;ks++){
        short8 b = *(const short8*)(P.pB2b + ((nt*4+ks)*64 + lane)*8);
        c = MFMA(a[ks], b, c);
      }
      #pragma unroll
      for(int j=0;j<4;j++){
        int row=rbase+j;
        if(row<NT) P.ebW2[(size_t)row*128 + nt*16+cl] = f2bf(__expf(c[j]));
      }
    }
  }
}

// fused pair (rel3, rel0): gather t3 + rs0; rs3 = lrelu(t3@Wrel3) in-register; 2 scores; RMW; 2 emits
__global__ __launch_bounds__(256) void k_fp0(PArgs P)
{
  __shared__ u16 lds1[64*LSTR];   // t3 (A-layout consumption)
  __shared__ u16 lds2[64*LSTR];   // rs0
  int tid = threadIdx.x;
  int base64 = blockIdx.x*64;
  gatherR3(lds1, P.sew, P.emb16, P.ssrc, P.starts_g, P.ends_g, base64, tid);
  gatherAtt(lds2, P.ebR2, P.emb16, P.ssrc, P.starts_g, P.ends_g, P.r2, base64, tid);
  __syncthreads();
  int wave=tid>>6, lane=tid&63;
  int base = base64 + wave*16;
  if(base >= NT) return;
  int arow = base + (lane&15); if(arow >= NT) arow = NT-1;
  int kof = (lane>>4)*8;
  int lar = wave*16 + (lane&15);     // local A row for t3
  short8 a[4];
  #pragma unroll
  for(int ks=0;ks<4;ks++) a[ks] = *(const short8*)(P.emb16 + (size_t)arow*128 + ks*32 + kof);
  // rs3 = lrelu(t3 @ Wrel3)  (C-layout registers)
  f32x4 rs3[8];
  {
    short8 ta[4];
    #pragma unroll
    for(int ks=0;ks<4;ks++) ta[ks] = *(const short8*)(lds1 + lar*LSTR + ks*32 + kof);
    #pragma unroll
    for(int nt=0;nt<8;nt++){
      f32x4 c = {0.f,0.f,0.f,0.f};
      #pragma unroll
      for(int ks=0;ks<4;ks++){
        short8 b = *(const short8*)(P.pWr3 + ((nt*4+ks)*64 + lane)*8);
        c = MFMA(ta[ks], b, c);
      }
      #pragma unroll
      for(int j=0;j<4;j++) c[j] = lrelu(c[j]);
      rs3[nt]=c;
    }
  }
  int rbase = base + (lane>>4)*4;
  int lrb   = wave*16 + (lane>>4)*4;
  int cl = lane&15;
  int bias = *P.bflag;
  float e1v[4], e2v[4];
  // --- score rel3 (rs from registers) ---
  {
    f32x4 accS[8];
    #pragma unroll
    for(int nt=0;nt<8;nt++){
      f32x4 c = {0.f,0.f,0.f,0.f};
      #pragma unroll
      for(int ks=0;ks<4;ks++){
        short8 b = *(const short8*)(P.pA1 + ((nt*4+ks)*64 + lane)*8);
        c = MFMA(a[ks], b, c);
      }
      accS[nt]=c;
    }
    float prival = P.p1[0]*0.08838834764831845f;
    #pragma unroll
    for(int j=0;j<4;j++){
      int row=rbase+j; bool ok=row<NT;
      float p=0.f;
      if(ok){
        #pragma unroll
        for(int nt=0;nt<8;nt++){
          int col=nt*16+cl;
          float rv = rs3[nt][j];
          p += accS[nt][j]*rv;
          if(bias) p += bf2f(P.emb16[(size_t)row*128+col])*P.u1[col] + rv*P.w1[col];
        }
      }
      p += __shfl_xor(p,1,16); p += __shfl_xor(p,2,16);
      p += __shfl_xor(p,4,16); p += __shfl_xor(p,8,16);
      e1v[j] = __expf((p + P.c1[0])*prival);
    }
  }
  // --- score rel0 (rs from LDS) ---
  {
    f32x4 accS[8];
    #pragma unroll
    for(int nt=0;nt<8;nt++){
      f32x4 c = {0.f,0.f,0.f,0.f};
      #pragma unroll
      for(int ks=0;ks<4;ks++){
        short8 b = *(const short8*)(P.pA2 + ((nt*4+ks)*64 + lane)*8);
        c = MFMA(a[ks], b, c);
      }
      accS[nt]=c;
    }
    float prival = P.p2[0]*0.08838834764831845f;
    #pragma unroll
    for(int j=0;j<4;j++){
      int row=rbase+j; bool ok=row<NT;
      float p=0.f;
      if(ok){
        #pragma unroll
        for(int nt=0;nt<8;nt++){
          int col=nt*16+cl;
          float rv = bf2f(lds2[(lrb+j)*LSTR+col]);
          p += accS[nt][j]*rv;
          if(bias) p += bf2f(P.emb16[(size_t)row*128+col])*P.u2[col] + rv*P.w2[col];
        }
      }
      p += __shfl_xor(p,1,16); p += __shfl_xor(p,2,16);
      p += __shfl_xor(p,4,16); p += __shfl_xor(p,8,16);
      e2v[j] = __expf((p + P.c2[0])*prival);
    }
  }
  // --- RMW (rs3 from regs; note rs3 values are bf16-equivalent of prior rounds within rounding) ---
  #pragma unroll
  for(int j=0;j<4;j++){
    int row=rbase+j;
    if(row<NT){
      float ee1=e1v[j], ee2=e2v[j];
      #pragma unroll
      for(int nt=0;nt<8;nt++){
        int col=nt*16+cl;
        size_t o=(size_t)row*128+col;
        float add = ee1*bf2f(f2bf(rs3[nt][j])) + ee2*bf2f(lds2[(lrb+j)*LSTR+col]);
        P.acc16[o] = f2bf(bf2f(P.acc16[o]) + add);
      }
      if(cl==0) P.den[row] += ee1 + ee2;
    }
  }
  // --- emit ebot for rel1, rel2 ---
  #pragma unroll
  for(int nt=0;nt<8;nt++){
    f32x4 c = {0.f,0.f,0.f,0.f};
    #pragma unroll
    for(int ks=0;ks<4;ks++){
      short8 b = *(const short8*)(P.pB2a + ((nt*4+ks)*64 + lane)*8);
      c = MFMA(a[ks], b, c);
    }
    #pragma unroll
    for(int j=0;j<4;j++){
      int row=rbase+j;
      if(row<NT) P.ebW1[(size_t)row*128 + nt*16+cl] = f2bf(__expf(c[j]));
    }
  }
  #pragma unroll
  for(int nt=0;nt<8;nt++){
    f32x4 c = {0.f,0.f,0.f,0.f};
    #pragma unroll
    for(int ks=0;ks<4;ks++){
      short8 b = *(const short8*)(P.pB2b + ((nt*4+ks)*64 + lane)*8);
      c = MFMA(a[ks], b, c);
    }
    #pragma unroll
    for(int j=0;j<4;j++){
      int row=rbase+j;
      if(row<NT) P.ebW2[(size_t)row*128 + nt*16+cl] = f2bf(__expf(c[j]));
    }
  }
}

extern "C" void kernel_launch(void* const* d_in, const int* in_sizes, int n_in,
                              void* d_out, int out_size, void* d_ws, size_t ws_size,
                              hipStream_t stream){
  const float* company = (const float*)d_in[0];
  const float* person  = (const float*)d_in[1];
  const float* eweight = (const float*)d_in[2];
  const float* W_com   = (const float*)d_in[3];
  const float* W_per   = (const float*)d_in[4];
  const float* Wq      = (const float*)d_in[5];
  const float* bq      = (const float*)d_in[6];
  const float* Wk      = (const float*)d_in[7];
  const float* bk      = (const float*)d_in[8];
  const float* Wv      = (const float*)d_in[9];
  const float* bvv     = (const float*)d_in[10];
  const float* pri     = (const float*)d_in[11];
  const float* Wpair   = (const float*)d_in[12];
  const float* Wrel3   = (const float*)d_in[13];
  const float* skip    = (const float*)d_in[14];
  const int*   eidx    = (const int*)d_in[15];
  float* out = (float*)d_out;

  // workspace (~181 MB, known-good level)
  char* w = (char*)d_ws;
  auto alloc = [&](size_t sz)->void*{ void* p=(void*)w; w += (sz+255)&~(size_t)255; return p; };
  u16*   emb16 = (u16*)alloc((size_t)NT*128*2);        // 38.4 MB
  u16*   ebA   = (u16*)alloc((size_t)NT*128*2);        // 38.4 MB (aliases sort bsrc/bkey/bew)
  u16*   ebB   = (u16*)alloc((size_t)NT*128*2);        // 38.4 MB
  u16*   acc16 = (u16*)alloc((size_t)NT*128*2);        // 38.4 MB (aliases gcntT/poffT/btot/bbase)
  float* den   = (float*)alloc((size_t)NT*4);
  int*   starts_g = (int*)alloc((size_t)NSEG*4);
  int*   ends_g   = (int*)alloc((size_t)NSEG*4);
  int*   ssrc  = (int*)alloc((size_t)ETOT*4);
  float* sew   = (float*)alloc((size_t)ETOT*4);
  float* Ar    = (float*)alloc((size_t)RREL*16384*4);
  float* ur    = (float*)alloc(RREL*128*4);
  float* wr    = (float*)alloc(RREL*128*4);
  float* cr    = (float*)alloc(RREL*4);
  int*   bflag = (int*)alloc(256);
  u16* pWcom  = (u16*)alloc(16384*2);
  u16* pWper  = (u16*)alloc(16384*2);
  u16* pWrel3 = (u16*)alloc(16384*2);
  u16* pWv    = (u16*)alloc(16384*2);
  u16* pAr    = (u16*)alloc((size_t)RREL*16384*2);
  u16* pWbot  = (u16*)alloc((size_t)6*16384*2);
  (void)ws_size; (void)in_sizes; (void)n_in; (void)out_size;

  // ebC/ebD live in d_out (dead until final GEMM)
  u16* ebC = (u16*)d_out;
  u16* ebD = ebC + (size_t)NT*128;

  // sort temporaries alias dead regions
  int*   bsrc  = (int*)ebA;
  int*   bkey  = bsrc + ETOT;
  float* bew   = (float*)(bkey + ETOT);
  int*   gcntT = (int*)acc16;
  int*   poffT = gcntT + P1B*NBUK;
  int*   btot  = poffT + P1B*NBUK;
  int*   bbase = btot + NBUK;

  hipMemsetAsync(den, 0, (size_t)NT*4, stream);
  hipMemsetAsync(bflag, 0, 4, stream);

  k_bin<<<P1B,256,0,stream>>>(eidx, eweight, bsrc, bkey, bew, gcntT, poffT);
  k_bsum<<<NBUK,256,0,stream>>>(gcntT, btot);
  k_bscan<<<1,256,0,stream>>>(btot, bbase);
  k_place<<<NBUK,256,0,stream>>>(bsrc,bkey,bew,gcntT,poffT,bbase,
                                 starts_g,ends_g,ssrc,sew);
  hipMemsetAsync(acc16, 0, (size_t)NT*128*2, stream);

  k_prep<<<(RREL*16384+255)/256,256,0,stream>>>(Wq,bq,Wk,bk,Ar,ur,wr,cr,bflag);

  const int attr[6] = {0,1,2,4,5,6};
  PackJobs pj{};
  int nj=0;
  auto addjob=[&](const float* s,u16* d,int ks){ pj.j[nj].src=s; pj.j[nj].dst=d; pj.j[nj].ksteps=ks; nj++; };
  addjob(W_com,pWcom,4); addjob(W_per,pWper,4);
  addjob(Wrel3,pWrel3,4); addjob(Wv,pWv,4);
  for(int r=0;r<RREL;r++) addjob(Ar + (size_t)r*16384, pAr + (size_t)r*16384, 4);
  for(int i=0;i<6;i++) addjob(Wpair + (size_t)attr[i]*32768 + 16384, pWbot + (size_t)i*16384, 4);
  dim3 pg(16, nj);
  k_pack<<<pg,256,0,stream>>>(pj);

  GArgs g{};
  g = GArgs{}; g.A=company; g.B=pWcom; g.M=NCY; g.rowoff=0; g.outH=emb16;
  k_gemm<0,1><<<(NCY+63)/64,256,0,stream>>>(g);
  g = GArgs{}; g.A=person; g.B=pWper; g.M=NPR; g.rowoff=NCY; g.outH=emb16;
  k_gemm<0,1><<<(NPR+63)/64,256,0,stream>>>(g);

  // bootstrap: ebA = exp(emb @ Wbot[rel0])
  g = GArgs{}; g.A=emb16; g.B=pWbot; g.M=NT; g.outH=ebA;
  k_gemm<4,0><<<(NT+63)/64,256,0,stream>>>(g);

  int NBLK = (NT+63)/64;
  auto mkP = [&](int r1,int r2,const u16* eb1,const u16* eb2,
                 int sa,int sb,u16* w1,u16* w2)->PArgs{
    PArgs P{};
    P.emb16=emb16; P.ssrc=ssrc; P.starts_g=starts_g; P.ends_g=ends_g; P.sew=sew;
    P.ebR1=eb1; P.ebR2=eb2;
    P.pA1=pAr+(size_t)r1*16384; P.pA2=pAr+(size_t)r2*16384;
    P.pWr3=pWrel3;
    P.pB2a=(sa>=0)? pWbot+(size_t)sa*16384 : nullptr;
    P.pB2b=(sb>=0)? pWbot+(size_t)sb*16384 : nullptr;
    P.ebW1=w1; P.ebW2=w2;
    P.acc16=acc16; P.den=den;
    P.u1=ur+(size_t)r1*128; P.w1=wr+(size_t)r1*128; P.c1=cr+r1; P.p1=pri+r1;
    P.u2=ur+(size_t)r2*128; P.w2=wr+(size_t)r2*128; P.c2=cr+r2; P.p2=pri+r2;
    P.bflag=bflag; P.r1=r1; P.r2=r2;
    return P;
  };

  // pair (3,0): gathers t3 + rs0(ebA); emits ebot(rel1)->ebC, ebot(rel2)->ebD
  k_fp0<<<NBLK,256,0,stream>>>(mkP(3,0, nullptr,ebA, 1,2, ebC,ebD));
  // pair (1,2): gathers rs1(ebC), rs2(ebD); emits ebot(rel4)->ebA, ebot(rel5)->ebB
  k_fp<2,2><<<NBLK,256,0,stream>>>(mkP(1,2, ebC,ebD, 3,4, ebA,ebB));
  // pair (4,5): gathers rs4(ebA), rs5(ebB); emits ebot(rel6)->ebC
  k_fp<2,1><<<NBLK,256,0,stream>>>(mkP(4,5, ebA,ebB, 5,-1, ebC,nullptr));
  // single (6): gathers rs6(ebC); no emit
  k_fp<1,0><<<NBLK,256,0,stream>>>(mkP(6,6, ebC,nullptr, -1,-1, nullptr,nullptr));

  // final: out = (acc16/den)@Wv + bv + sigmoid(skip)*gelu(emb)
  g = GArgs{}; g.A=acc16; g.B=pWv; g.M=NT;
  g.acc=out; g.den=den; g.emb16=emb16; g.bv=bvv; g.skip=skip;
  k_gemm<3,3><<<(NT+63)/64,256,0,stream>>>(g);
}